// Round 1
// baseline (634.291 us; speedup 1.0000x reference)
//
#include <hip/hip_runtime.h>
#include <math.h>

#define BB 2
#define LL 2048
#define DIMV 1024
#define SSV 16
#define INNERV 1024
#define E2V 2048
#define MMV (BB*LL)      // 4096 rows
#define NCHUNK 32
#define CLEN 64          // LL / NCHUNK

static __device__ __forceinline__ float4 ld4(const float* p){
  return *reinterpret_cast<const float4*>(p);
}

// ---------------- LayerNorm: h = LN(x)*gamma + beta ----------------
__global__ __launch_bounds__(256) void ln_kernel(const float* __restrict__ x,
        const float* __restrict__ gamma, const float* __restrict__ beta,
        float* __restrict__ h){
  int row = blockIdx.x;
  int tid = threadIdx.x;
  const float* xr = x + (size_t)row*DIMV;
  float4 v = ld4(xr + tid*4);
  float s  = v.x+v.y+v.z+v.w;
  float s2 = v.x*v.x+v.y*v.y+v.z*v.z+v.w*v.w;
  for (int o=32;o;o>>=1){ s += __shfl_down(s,o); s2 += __shfl_down(s2,o); }
  __shared__ float red[8];
  int wid = tid>>6, lane = tid&63;
  if (lane==0){ red[wid]=s; red[4+wid]=s2; }
  __syncthreads();
  s  = red[0]+red[1]+red[2]+red[3];
  s2 = red[4]+red[5]+red[6]+red[7];
  float mu  = s*(1.f/DIMV);
  float var = s2*(1.f/DIMV) - mu*mu;
  float rstd = rsqrtf(var + 1e-5f);
  float4 g = ld4(gamma + tid*4), be = ld4(beta + tid*4);
  float4 o;
  o.x = (v.x-mu)*rstd*g.x + be.x;
  o.y = (v.y-mu)*rstd*g.y + be.y;
  o.z = (v.z-mu)*rstd*g.z + be.z;
  o.w = (v.w-mu)*rstd*g.w + be.w;
  *reinterpret_cast<float4*>(h + (size_t)row*DIMV + tid*4) = o;
}

// ---------------- fp32 GEMM: Co[M,N] = A[M,K] * Bw[N,K]^T (+epilogue) ----------------
// EPI 0: plain store. EPI 1: v += aux[col]; softplus. EPI 2: v += aux[row*N+col].
#define GBM 128
#define GBN 128
#define GBK 16
#define GPAD 4

template<int EPI>
__global__ __launch_bounds__(256) void gemm_tn(const float* __restrict__ A,
        const float* __restrict__ Bw, float* __restrict__ Co,
        int N, int Kd, const float* __restrict__ aux){
  __shared__ float As[GBK][GBM+GPAD];
  __shared__ float Bs[GBK][GBN+GPAD];
  int tid = threadIdx.x;
  int bm = blockIdx.y * GBM, bn = blockIdx.x * GBN;
  int sr = tid >> 1;          // 0..127 row within tile
  int sk = (tid & 1) * 8;     // 0 or 8
  const float* Ap = A  + (size_t)(bm+sr)*Kd + sk;
  const float* Bp = Bw + (size_t)(bn+sr)*Kd + sk;
  int tx = tid & 15, ty = tid >> 4;
  float acc[8][8];
  #pragma unroll
  for (int i=0;i<8;i++){
    #pragma unroll
    for (int j=0;j<8;j++) acc[i][j] = 0.f;
  }
  float4 a0r = ld4(Ap), a1r = ld4(Ap+4);
  float4 b0r = ld4(Bp), b1r = ld4(Bp+4);
  int nk = Kd / GBK;
  for (int kt=0; kt<nk; ++kt){
    __syncthreads();
    As[sk+0][sr]=a0r.x; As[sk+1][sr]=a0r.y; As[sk+2][sr]=a0r.z; As[sk+3][sr]=a0r.w;
    As[sk+4][sr]=a1r.x; As[sk+5][sr]=a1r.y; As[sk+6][sr]=a1r.z; As[sk+7][sr]=a1r.w;
    Bs[sk+0][sr]=b0r.x; Bs[sk+1][sr]=b0r.y; Bs[sk+2][sr]=b0r.z; Bs[sk+3][sr]=b0r.w;
    Bs[sk+4][sr]=b1r.x; Bs[sk+5][sr]=b1r.y; Bs[sk+6][sr]=b1r.z; Bs[sk+7][sr]=b1r.w;
    __syncthreads();
    if (kt+1 < nk){
      Ap += GBK; Bp += GBK;
      a0r = ld4(Ap); a1r = ld4(Ap+4); b0r = ld4(Bp); b1r = ld4(Bp+4);
    }
    #pragma unroll
    for (int kk=0; kk<GBK; kk++){
      float4 A0 = *(const float4*)&As[kk][ty*4];
      float4 A1 = *(const float4*)&As[kk][64+ty*4];
      float4 B0 = *(const float4*)&Bs[kk][tx*4];
      float4 B1 = *(const float4*)&Bs[kk][64+tx*4];
      float av[8] = {A0.x,A0.y,A0.z,A0.w,A1.x,A1.y,A1.z,A1.w};
      float bv[8] = {B0.x,B0.y,B0.z,B0.w,B1.x,B1.y,B1.z,B1.w};
      #pragma unroll
      for (int i=0;i<8;i++){
        #pragma unroll
        for (int j=0;j<8;j++) acc[i][j] = fmaf(av[i], bv[j], acc[i][j]);
      }
    }
  }
  #pragma unroll
  for (int i=0;i<8;i++){
    int r = bm + (i<4 ? ty*4+i : 64+ty*4+(i-4));
    #pragma unroll
    for (int j=0;j<8;j++){
      int c = bn + (j<4 ? tx*4+j : 64+tx*4+(j-4));
      float v = acc[i][j];
      if (EPI==1){ v += aux[c]; v = (v > 20.f) ? v : log1pf(expf(v)); }
      if (EPI==2){ v += aux[(size_t)r*N + c]; }
      Co[(size_t)r*N + c] = v;
    }
  }
}

// ---------------- depthwise conv(K=3, pad=1) + silu ----------------
__global__ __launch_bounds__(256) void conv_silu_kernel(const float* __restrict__ xz,
        const float* __restrict__ cw, float* __restrict__ xc){
  int idx = blockIdx.x*256 + threadIdx.x;   // MMV * DIMV/4 threads
  int d4  = idx & 255;                      // DIMV/4 = 256
  int row = idx >> 8;
  int t = row & (LL-1);
  const float* p = xz + (size_t)row*E2V + d4*4;   // xx = first INNER cols of xz
  float4 x1 = ld4(p);
  float4 x0 = (t>0)    ? ld4(p - E2V) : make_float4(0.f,0.f,0.f,0.f);
  float4 x2 = (t<LL-1) ? ld4(p + E2V) : make_float4(0.f,0.f,0.f,0.f);
  int d = d4*4;
  float w[12];
  #pragma unroll
  for (int i=0;i<12;i++) w[i] = cw[d*3 + i];
  float4 o;
  o.x = x0.x*w[0] + x1.x*w[1]  + x2.x*w[2];
  o.y = x0.y*w[3] + x1.y*w[4]  + x2.y*w[5];
  o.z = x0.z*w[6] + x1.z*w[7]  + x2.z*w[8];
  o.w = x0.w*w[9] + x1.w*w[10] + x2.w*w[11];
  o.x = o.x / (1.f + __expf(-o.x));
  o.y = o.y / (1.f + __expf(-o.y));
  o.z = o.z / (1.f + __expf(-o.z));
  o.w = o.w / (1.f + __expf(-o.w));
  *reinterpret_cast<float4*>(xc + (size_t)row*DIMV + d4*4) = o;
}

// ---------------- W_x transpose (32x1024 -> 1024x32) ----------------
__global__ __launch_bounds__(256) void transpose_wx_kernel(const float* __restrict__ wx,
        float* __restrict__ wxt){
  int idx = blockIdx.x*256 + threadIdx.x;   // 32*1024
  int e = idx >> 10, k = idx & 1023;
  wxt[k*32 + e] = wx[idx];
}

// ---------------- BC = xc @ W_x^T  (N=32) ----------------
__global__ __launch_bounds__(256) void bc_kernel(const float* __restrict__ xc,
        const float* __restrict__ wxt, float* __restrict__ bc){
  __shared__ float sxc[8][1024];
  int tid = threadIdx.x;
  int row0 = blockIdx.x * 8;
  const float4* src = (const float4*)(xc + (size_t)row0*DIMV);
  #pragma unroll
  for (int i=0;i<8;i++)
    ((float4*)&sxc[0][0])[tid + i*256] = src[tid + i*256];
  __syncthreads();
  int r = tid >> 5, e = tid & 31;
  float acc = 0.f;
  for (int k=0;k<1024;k+=4){
    float4 xv = *(const float4*)&sxc[r][k];
    acc = fmaf(xv.x, wxt[(k+0)*32+e], acc);
    acc = fmaf(xv.y, wxt[(k+1)*32+e], acc);
    acc = fmaf(xv.z, wxt[(k+2)*32+e], acc);
    acc = fmaf(xv.w, wxt[(k+3)*32+e], acc);
  }
  bc[(size_t)(row0 + r)*32 + e] = acc;
}

// ---------------- chunked scan, pass 1: per-chunk local F, P ----------------
__global__ __launch_bounds__(256) void scan_p1(const float* __restrict__ dt,
        const float* __restrict__ bc, const float* __restrict__ A_log,
        float* __restrict__ F, float* __restrict__ P){
  int bid = blockIdx.x;           // b*(32*64) + c*64 + db
  int db = bid & 63;
  int c  = (bid >> 6) & 31;
  int b  = bid >> 11;
  int g = threadIdx.x >> 4, s = threadIdx.x & 15;
  int d = db*16 + g;
  float a = -expf(A_log[d*SSV + s]);
  float st = 0.f, p = 1.f;
  int row0 = b*LL + c*CLEN;
  const float* dtp = dt + (size_t)row0*DIMV + d;
  const float* bp  = bc + (size_t)row0*32 + s;
  #pragma unroll 4
  for (int t=0;t<CLEN;t++){
    float dtv = dtp[t*DIMV];
    float Bv  = bp[t*32];
    float dA  = __expf(dtv*a);
    st = fmaf(st, dA, dtv*Bv);
    p *= dA;
  }
  int o = (((b*NCHUNK + c)*DIMV + d)<<4) + s;
  F[o] = st; P[o] = p;
}

// ---------------- pass 2: serial combine over chunks ----------------
__global__ __launch_bounds__(256) void scan_p2(const float* __restrict__ F,
        const float* __restrict__ P, float* __restrict__ E){
  int idx = blockIdx.x*256 + threadIdx.x;   // BB*DIMV*SSV = 32768
  int b  = idx >> 14;
  int ds = idx & 16383;
  float e = 0.f;
  #pragma unroll
  for (int c=0;c<NCHUNK;c++){
    int o = ((b*NCHUNK + c) << 14) + ds;
    E[o] = e;
    e = fmaf(P[o], e, F[o]);
  }
}

// ---------------- pass 3: replay with true entry state, fuse gating ----------------
__global__ __launch_bounds__(256) void scan_p3(const float* __restrict__ dt,
        const float* __restrict__ bc, const float* __restrict__ A_log,
        const float* __restrict__ E, const float* __restrict__ xc,
        const float* __restrict__ xz, const float* __restrict__ Dp,
        float* __restrict__ yf){
  int bid = blockIdx.x;
  int db = bid & 63;
  int c  = (bid >> 6) & 31;
  int b  = bid >> 11;
  int g = threadIdx.x >> 4, s = threadIdx.x & 15;
  int d = db*16 + g;
  float a = -expf(A_log[d*SSV + s]);
  float st = E[(((b*NCHUNK + c)*DIMV + d)<<4) + s];
  float Dv = Dp[d];
  int row0 = b*LL + c*CLEN;
  const float* dtp = dt + (size_t)row0*DIMV + d;
  const float* bp  = bc + (size_t)row0*32;
  for (int t=0;t<CLEN;t++){
    float dtv = dtp[t*DIMV];
    float Bv  = bp[t*32 + s];
    float Cv  = bp[t*32 + 16 + s];
    float dA  = __expf(dtv*a);
    st = fmaf(st, dA, dtv*Bv);
    float y = st*Cv;
    y += __shfl_xor(y, 8, 16);
    y += __shfl_xor(y, 4, 16);
    y += __shfl_xor(y, 2, 16);
    y += __shfl_xor(y, 1, 16);
    if (s==0){
      int row = row0 + t;
      float xcv = xc[(size_t)row*DIMV + d];
      float zv  = xz[(size_t)row*E2V + INNERV + d];
      float sz  = zv / (1.f + __expf(-zv));
      yf[(size_t)row*DIMV + d] = (y + Dv*xcv)*sz;
    }
  }
}

extern "C" void kernel_launch(void* const* d_in, const int* in_sizes, int n_in,
                              void* d_out, int out_size, void* d_ws, size_t ws_size,
                              hipStream_t stream){
  const float* x     = (const float*)d_in[0];
  const float* gamma = (const float*)d_in[1];
  const float* beta  = (const float*)d_in[2];
  const float* W_in  = (const float*)d_in[3];
  const float* cw    = (const float*)d_in[4];
  const float* W_x   = (const float*)d_in[5];
  const float* W_dt  = (const float*)d_in[6];
  const float* b_dt  = (const float*)d_in[7];
  const float* A_log = (const float*)d_in[8];
  const float* Dp    = (const float*)d_in[9];
  const float* W_out = (const float*)d_in[10];
  float* out = (float*)d_out;
  float* ws  = (float*)d_ws;
  const size_t MB = (size_t)1 << 20;   // 1M floats
  float* h   = ws;             // 4M floats
  float* xz  = ws + 4*MB;      // 8M floats
  float* xc  = ws + 12*MB;     // 4M floats
  float* dtb = ws + 16*MB;     // 4M floats
  float* bcb = ws + 20*MB;     // 128K floats
  float* wxt = ws + 21*MB;     // 32K floats
  float* F   = ws + 22*MB;     // 1M floats
  float* P   = ws + 23*MB;     // 1M floats
  float* E   = ws + 24*MB;     // 1M floats
  float* yf  = h;              // h is dead after gemm_xz -> reuse

  ln_kernel<<<MMV, 256, 0, stream>>>(x, gamma, beta, h);
  gemm_tn<0><<<dim3(E2V/GBN, MMV/GBM), 256, 0, stream>>>(h, W_in, xz, E2V, DIMV, nullptr);
  conv_silu_kernel<<<(MMV*(DIMV/4))/256, 256, 0, stream>>>(xz, cw, xc);
  gemm_tn<1><<<dim3(INNERV/GBN, MMV/GBM), 256, 0, stream>>>(xc, W_dt, dtb, INNERV, INNERV, b_dt);
  transpose_wx_kernel<<<(32*1024)/256, 256, 0, stream>>>(W_x, wxt);
  bc_kernel<<<MMV/8, 256, 0, stream>>>(xc, wxt, bcb);
  scan_p1<<<BB*NCHUNK*(DIMV/16), 256, 0, stream>>>(dtb, bcb, A_log, F, P);
  scan_p2<<<(BB*DIMV*SSV)/256, 256, 0, stream>>>(F, P, E);
  scan_p3<<<BB*NCHUNK*(DIMV/16), 256, 0, stream>>>(dtb, bcb, A_log, E, xc, xz, Dp, yf);
  gemm_tn<2><<<dim3(DIMV/GBN, MMV/GBM), 256, 0, stream>>>(yf, W_out, out, DIMV, INNERV, x);
}

// Round 3
// 361.064 us; speedup vs baseline: 1.7567x; 1.7567x over previous
//
#include <hip/hip_runtime.h>
#include <math.h>

#define BB 2
#define LL 2048
#define DIMV 1024
#define SSV 16
#define INNERV 1024
#define E2V 2048
#define MMV (BB*LL)      // 4096 rows
#define NCHUNK 32
#define CLEN 64          // LL / NCHUNK

typedef __attribute__((ext_vector_type(8))) short short8;   // 8 bf16 = 4 VGPRs (MFMA A/B frag)
typedef __attribute__((ext_vector_type(4))) float f32x4;    // MFMA C/D frag

static __device__ __forceinline__ float4 ld4(const float* p){
  return *reinterpret_cast<const float4*>(p);
}
// RNE fp32 -> bf16 (bit-level)
static __device__ __forceinline__ ushort f2bf(float x){
  unsigned u = __float_as_uint(x);
  unsigned r = (u + 0x7fffu + ((u >> 16) & 1u)) >> 16;
  return (ushort)r;
}
static __device__ __forceinline__ float bf2f(ushort h){
  return __uint_as_float(((unsigned)h) << 16);
}
static __device__ __forceinline__ void split1(float x, ushort& h, ushort& l){
  h = f2bf(x);
  l = f2bf(x - bf2f(h));
}
// async global->LDS, 16B per lane; lds dest wave-uniform base + lane*16
static __device__ __forceinline__ void gld16(const void* g, void* l){
  __builtin_amdgcn_global_load_lds(
      (const __attribute__((address_space(1))) void*)g,
      (__attribute__((address_space(3))) void*)l, 16, 0, 0);
}

// ---------------- LayerNorm -> split bf16 hi/lo ----------------
__global__ __launch_bounds__(256) void ln_kernel(const float* __restrict__ x,
        const float* __restrict__ gamma, const float* __restrict__ beta,
        ushort* __restrict__ hh, ushort* __restrict__ hl){
  int row = blockIdx.x;
  int tid = threadIdx.x;
  const float* xr = x + (size_t)row*DIMV;
  float4 v = ld4(xr + tid*4);
  float s  = v.x+v.y+v.z+v.w;
  float s2 = v.x*v.x+v.y*v.y+v.z*v.z+v.w*v.w;
  for (int o=32;o;o>>=1){ s += __shfl_down(s,o); s2 += __shfl_down(s2,o); }
  __shared__ float red[8];
  int wid = tid>>6, lane = tid&63;
  if (lane==0){ red[wid]=s; red[4+wid]=s2; }
  __syncthreads();
  s  = red[0]+red[1]+red[2]+red[3];
  s2 = red[4]+red[5]+red[6]+red[7];
  float mu  = s*(1.f/DIMV);
  float var = s2*(1.f/DIMV) - mu*mu;
  float rstd = rsqrtf(var + 1e-5f);
  float4 g = ld4(gamma + tid*4), be = ld4(beta + tid*4);
  float o0 = (v.x-mu)*rstd*g.x + be.x;
  float o1 = (v.y-mu)*rstd*g.y + be.y;
  float o2 = (v.z-mu)*rstd*g.z + be.z;
  float o3 = (v.w-mu)*rstd*g.w + be.w;
  ushort4 H, L;
  split1(o0,H.x,L.x); split1(o1,H.y,L.y); split1(o2,H.z,L.z); split1(o3,H.w,L.w);
  *reinterpret_cast<ushort4*>(hh + (size_t)row*DIMV + tid*4) = H;
  *reinterpret_cast<ushort4*>(hl + (size_t)row*DIMV + tid*4) = L;
}

// ---------------- weight split: fp32[n] -> bf16 hi/lo ----------------
__global__ __launch_bounds__(256) void wsplit(const float* __restrict__ src,
        ushort* __restrict__ hi, ushort* __restrict__ lo, int n4){
  int i = blockIdx.x*256 + threadIdx.x;
  if (i >= n4) return;
  float4 v = ld4(src + (size_t)i*4);
  ushort4 H, L;
  split1(v.x,H.x,L.x); split1(v.y,H.y,L.y); split1(v.z,H.z,L.z); split1(v.w,H.w,L.w);
  *reinterpret_cast<ushort4*>(hi + (size_t)i*4) = H;
  *reinterpret_cast<ushort4*>(lo + (size_t)i*4) = L;
}

// ============ split-bf16 MFMA GEMM: Co[M,N] = A[M,1024]*Bw[N,1024]^T ============
// m97-canonical 2-barrier-per-K-step, SINGLE LDS buffer (race-proof template).
// BM=128, BN=64, BK=32, 256 thr (2m x 2n waves; wave tile 64x32).
// LDS: Ah[128x32] Al Bh[64x32] Bl bf16, 16B-unit XOR swizzle
// (physical slot p holds logical unit p^(row&3); staged via inverse-swizzled
// global source, read with the same XOR — rule 21 both-sides scheme).
#define GBK 32
#define NKT 32

template<int EPI>
__global__ __launch_bounds__(256) void gemm_bf16s(
    const ushort* __restrict__ Ah, const ushort* __restrict__ Al,
    const ushort* __restrict__ Bh, const ushort* __restrict__ Bl,
    float* __restrict__ Co, int N, const float* __restrict__ aux){
  __shared__ __align__(16) ushort lds[12288];   // 24KB single buffer
  const int t  = threadIdx.x;
  const int bm = blockIdx.y * 128, bn = blockIdx.x * 64;

  // staging: physical 16B-unit index = t (row r4=t>>2, slot t&3);
  // logical unit fetched = (t&3)^(r4&3)
  const int r4 = t >> 2;
  const int k16 = (t & 3) ^ (r4 & 3);
  const ushort* gAh = Ah + (size_t)(bm + r4)*1024 + k16*8;
  const ushort* gAl = Al + (size_t)(bm + r4)*1024 + k16*8;
  const ushort* gBh = Bh + (size_t)(bn + r4)*1024 + k16*8;
  const ushort* gBl = Bl + (size_t)(bn + r4)*1024 + k16*8;
  const int wofs = (t >> 6) * 1024;     // per-wave byte offset inside 4KB segment

  // fragment reads (apply same XOR)
  const int l  = t & 63, wv = t >> 6;
  const int wm = wv & 1, wn = wv >> 1;
  const int fr = l & 15, kb = l >> 4;
  const int sw = (kb ^ (fr & 3)) * 16;
  const int aofs = (wm*64 + fr)*64 + sw;   // row stride 64B
  const int bofs = (wn*32 + fr)*64 + sw;

  f32x4 acc[4][2];
  #pragma unroll
  for (int m=0;m<4;m++){
    #pragma unroll
    for (int n=0;n<2;n++) acc[m][n] = (f32x4){0.f,0.f,0.f,0.f};
  }

  char* Lb = (char*)lds;
  for (int kt = 0; kt < NKT; ++kt){
    const int ko = kt*GBK;
    gld16(gAh + ko,           Lb +     0 + wofs);
    gld16(gAh + ko + 64*1024, Lb +  4096 + wofs);
    gld16(gAl + ko,           Lb +  8192 + wofs);
    gld16(gAl + ko + 64*1024, Lb + 12288 + wofs);
    gld16(gBh + ko,           Lb + 16384 + wofs);
    gld16(gBl + ko,           Lb + 20480 + wofs);
    __syncthreads();                       // drains vmcnt -> tile ready
    short8 ah[4], al[4], bh[2], bl[2];
    #pragma unroll
    for (int m=0;m<4;m++){
      ah[m] = *(const short8*)(Lb +        aofs + m*1024);
      al[m] = *(const short8*)(Lb + 8192 + aofs + m*1024);
    }
    #pragma unroll
    for (int n=0;n<2;n++){
      bh[n] = *(const short8*)(Lb + 16384 + bofs + n*1024);
      bl[n] = *(const short8*)(Lb + 20480 + bofs + n*1024);
    }
    #pragma unroll
    for (int m=0;m<4;m++){
      #pragma unroll
      for (int n=0;n<2;n++){
        acc[m][n] = __builtin_amdgcn_mfma_f32_16x16x32_bf16(ah[m], bh[n], acc[m][n], 0,0,0);
        acc[m][n] = __builtin_amdgcn_mfma_f32_16x16x32_bf16(al[m], bh[n], acc[m][n], 0,0,0);
        acc[m][n] = __builtin_amdgcn_mfma_f32_16x16x32_bf16(ah[m], bl[n], acc[m][n], 0,0,0);
      }
    }
    __syncthreads();                       // all reads done before next STAGE
  }

  // C/D layout: col = lane&15, row = (lane>>4)*4 + reg   [m89-verified]
  #pragma unroll
  for (int m=0;m<4;m++){
    int row0 = bm + wm*64 + m*16 + kb*4;
    #pragma unroll
    for (int n=0;n<2;n++){
      int col = bn + wn*32 + n*16 + fr;
      #pragma unroll
      for (int j=0;j<4;j++){
        int r = row0 + j;
        float v = acc[m][n][j];
        if (EPI==1){ v += aux[col]; v = (v > 20.f) ? v : log1pf(__expf(v)); }
        if (EPI==2){ v += aux[(size_t)r*N + col]; }
        Co[(size_t)r*N + col] = v;
      }
    }
  }
}

// ---------------- depthwise conv(K=3,pad=1) + silu -> bf16 hi/lo only ----------------
__global__ __launch_bounds__(256) void conv_silu_kernel(const float* __restrict__ xz,
        const float* __restrict__ cw, ushort* __restrict__ xch, ushort* __restrict__ xcl){
  int idx = blockIdx.x*256 + threadIdx.x;
  int d4  = idx & 255;
  int row = idx >> 8;
  int t = row & (LL-1);
  const float* p = xz + (size_t)row*E2V + d4*4;
  float4 x1 = ld4(p);
  float4 x0 = (t>0)    ? ld4(p - E2V) : make_float4(0.f,0.f,0.f,0.f);
  float4 x2 = (t<LL-1) ? ld4(p + E2V) : make_float4(0.f,0.f,0.f,0.f);
  int d = d4*4;
  float w[12];
  #pragma unroll
  for (int i=0;i<12;i++) w[i] = cw[d*3 + i];
  float4 o;
  o.x = x0.x*w[0] + x1.x*w[1]  + x2.x*w[2];
  o.y = x0.y*w[3] + x1.y*w[4]  + x2.y*w[5];
  o.z = x0.z*w[6] + x1.z*w[7]  + x2.z*w[8];
  o.w = x0.w*w[9] + x1.w*w[10] + x2.w*w[11];
  o.x = o.x / (1.f + __expf(-o.x));
  o.y = o.y / (1.f + __expf(-o.y));
  o.z = o.z / (1.f + __expf(-o.z));
  o.w = o.w / (1.f + __expf(-o.w));
  ushort4 H, L;
  split1(o.x,H.x,L.x); split1(o.y,H.y,L.y); split1(o.z,H.z,L.z); split1(o.w,H.w,L.w);
  *reinterpret_cast<ushort4*>(xch + (size_t)row*DIMV + d4*4) = H;
  *reinterpret_cast<ushort4*>(xcl + (size_t)row*DIMV + d4*4) = L;
}

// ---------------- W_x transpose (32x1024 -> 1024x32) ----------------
__global__ __launch_bounds__(256) void transpose_wx_kernel(const float* __restrict__ wx,
        float* __restrict__ wxt){
  int idx = blockIdx.x*256 + threadIdx.x;
  int e = idx >> 10, k = idx & 1023;
  wxt[k*32 + e] = wx[idx];
}

// ---------------- BC = xc @ W_x^T  (N=32), xc reconstructed hi+lo ----------------
__global__ __launch_bounds__(256) void bc_kernel(const ushort* __restrict__ xch,
        const ushort* __restrict__ xcl, const float* __restrict__ wxt,
        float* __restrict__ bc){
  __shared__ ushort sh[8192], sl[8192];
  int tid = threadIdx.x;
  int row0 = blockIdx.x * 8;
  const ushort4* srcH = (const ushort4*)(xch + (size_t)row0*DIMV);
  const ushort4* srcL = (const ushort4*)(xcl + (size_t)row0*DIMV);
  #pragma unroll
  for (int i=0;i<8;i++){
    ((ushort4*)sh)[tid + i*256] = srcH[tid + i*256];
    ((ushort4*)sl)[tid + i*256] = srcL[tid + i*256];
  }
  __syncthreads();
  int r = tid >> 5, e = tid & 31;
  float acc = 0.f;
  for (int k=0;k<1024;k++){
    float xv = bf2f(sh[r*1024+k]) + bf2f(sl[r*1024+k]);
    acc = fmaf(xv, wxt[k*32+e], acc);
  }
  bc[(size_t)(row0 + r)*32 + e] = acc;
}

// ---------------- chunked scan pass 1: per-chunk local (F, P) ----------------
__global__ __launch_bounds__(256) void scan_p1(const float* __restrict__ dt,
        const float* __restrict__ bc, const float* __restrict__ A_log,
        float* __restrict__ F, float* __restrict__ P){
  int bid = blockIdx.x;
  int db = bid & 63;
  int c  = (bid >> 6) & 31;
  int b  = bid >> 11;
  int g = threadIdx.x >> 4, s = threadIdx.x & 15;
  int d = db*16 + g;
  float a = -expf(A_log[d*SSV + s]);
  float st = 0.f, p = 1.f;
  int row0 = b*LL + c*CLEN;
  const float* dtp = dt + (size_t)row0*DIMV + d;
  const float* bp  = bc + (size_t)row0*32 + s;
  #pragma unroll 4
  for (int t=0;t<CLEN;t++){
    float dtv = dtp[t*DIMV];
    float Bv  = bp[t*32];
    float dA  = __expf(dtv*a);
    st = fmaf(st, dA, dtv*Bv);
    p *= dA;
  }
  int o = (((b*NCHUNK + c)*DIMV + d)<<4) + s;
  F[o] = st; P[o] = p;
}

// ---------------- pass 2: serial combine over chunks ----------------
__global__ __launch_bounds__(256) void scan_p2(const float* __restrict__ F,
        const float* __restrict__ P, float* __restrict__ E){
  int idx = blockIdx.x*256 + threadIdx.x;
  int b  = idx >> 14;
  int ds = idx & 16383;
  float e = 0.f;
  #pragma unroll
  for (int c=0;c<NCHUNK;c++){
    int o = ((b*NCHUNK + c) << 14) + ds;
    E[o] = e;
    e = fmaf(P[o], e, F[o]);
  }
}

// ---------------- pass 3: replay + fuse D*xc, silu(z); write y hi/lo bf16 ----------------
__global__ __launch_bounds__(256) void scan_p3(const float* __restrict__ dt,
        const float* __restrict__ bc, const float* __restrict__ A_log,
        const float* __restrict__ E, const ushort* __restrict__ xch,
        const ushort* __restrict__ xcl, const float* __restrict__ xz,
        const float* __restrict__ Dp,
        ushort* __restrict__ yh, ushort* __restrict__ yl){
  int bid = blockIdx.x;
  int db = bid & 63;
  int c  = (bid >> 6) & 31;
  int b  = bid >> 11;
  int g = threadIdx.x >> 4, s = threadIdx.x & 15;
  int d = db*16 + g;
  float a = -expf(A_log[d*SSV + s]);
  float st = E[(((b*NCHUNK + c)*DIMV + d)<<4) + s];
  float Dv = Dp[d];
  int row0 = b*LL + c*CLEN;
  const float* dtp = dt + (size_t)row0*DIMV + d;
  const float* bp  = bc + (size_t)row0*32;
  for (int t=0;t<CLEN;t++){
    float dtv = dtp[t*DIMV];
    float Bv  = bp[t*32 + s];
    float Cv  = bp[t*32 + 16 + s];
    float dA  = __expf(dtv*a);
    st = fmaf(st, dA, dtv*Bv);
    float y = st*Cv;
    y += __shfl_xor(y, 8, 16);
    y += __shfl_xor(y, 4, 16);
    y += __shfl_xor(y, 2, 16);
    y += __shfl_xor(y, 1, 16);
    if (s==0){
      int row = row0 + t;
      size_t ofs = (size_t)row*DIMV + d;
      float xcv = bf2f(xch[ofs]) + bf2f(xcl[ofs]);
      float zv  = xz[(size_t)row*E2V + INNERV + d];
      float sz  = zv / (1.f + __expf(-zv));
      float yv = (y + Dv*xcv)*sz;
      ushort H, L; split1(yv, H, L);
      yh[ofs] = H;
      yl[ofs] = L;
    }
  }
}

extern "C" void kernel_launch(void* const* d_in, const int* in_sizes, int n_in,
                              void* d_out, int out_size, void* d_ws, size_t ws_size,
                              hipStream_t stream){
  const float* x     = (const float*)d_in[0];
  const float* gamma = (const float*)d_in[1];
  const float* beta  = (const float*)d_in[2];
  const float* W_in  = (const float*)d_in[3];
  const float* cw    = (const float*)d_in[4];
  const float* W_x   = (const float*)d_in[5];
  const float* W_dt  = (const float*)d_in[6];
  const float* b_dt  = (const float*)d_in[7];
  const float* A_log = (const float*)d_in[8];
  const float* Dp    = (const float*)d_in[9];
  const float* W_out = (const float*)d_in[10];
  float* out = (float*)d_out;
  float* ws  = (float*)d_ws;
  const size_t MB = (size_t)1 << 20;   // 1M floats
  // layout (floats), max 24.16M floats = 96.6MB (round-1 proved >=100MB ok)
  float*  xz  = ws;                               // [0,8M)
  ushort* hh  = (ushort*)(ws + 8*MB);             // [8M,10M)  later yh
  ushort* hl  = (ushort*)(ws + 10*MB);            // [10M,12M) later yl
  float*  F   = ws + 8*MB;                        // [8M,9M)  after hh dead
  float*  P   = ws + 9*MB;                        // [9M,10M) after hh dead
  ushort* xch = (ushort*)(ws + 12*MB);            // [12M,14M)
  ushort* xcl = (ushort*)(ws + 14*MB);            // [14M,16M)
  ushort* Woh = (ushort*)(ws + 12*MB);            // [12M,12.5M) AFTER p3
  ushort* Wol = (ushort*)(ws + 12*MB + 512*1024); // [12.5M,13M) AFTER p3
  float*  dtb = ws + 16*MB;                       // [16M,20M)
  ushort* Wih = (ushort*)(ws + 20*MB);            // [20M,21M)
  ushort* Wil = (ushort*)(ws + 21*MB);            // [21M,22M)
  ushort* Wdh = (ushort*)(ws + 22*MB);            // [22M,22.5M)
  ushort* Wdl = (ushort*)(ws + 22*MB + 512*1024); // [22.5M,23M)
  float*  E   = ws + 23*MB;                       // [23M,24M)
  float*  bcb = ws + 24*MB;                       // 128K
  float*  wxt = ws + 24*MB + 256*1024;            // 32K
  ushort* yh = hh;
  ushort* yl = hl;

  wsplit<<<2048, 256, 0, stream>>>(W_in,  Wih, Wil, (2*INNERV*DIMV)/4);
  wsplit<<<1024, 256, 0, stream>>>(W_dt,  Wdh, Wdl, (INNERV*DIMV)/4);
  transpose_wx_kernel<<<(32*1024)/256, 256, 0, stream>>>(W_x, wxt);

  ln_kernel<<<MMV, 256, 0, stream>>>(x, gamma, beta, hh, hl);
  gemm_bf16s<0><<<dim3(E2V/64, MMV/128), 256, 0, stream>>>(hh, hl, Wih, Wil, xz, E2V, nullptr);
  conv_silu_kernel<<<(MMV*(DIMV/4))/256, 256, 0, stream>>>(xz, cw, xch, xcl);
  gemm_bf16s<1><<<dim3(INNERV/64, MMV/128), 256, 0, stream>>>(xch, xcl, Wdh, Wdl, dtb, INNERV, b_dt);
  bc_kernel<<<MMV/8, 256, 0, stream>>>(xch, xcl, wxt, bcb);
  scan_p1<<<BB*NCHUNK*(DIMV/16), 256, 0, stream>>>(dtb, bcb, A_log, F, P);
  scan_p2<<<(BB*DIMV*SSV)/256, 256, 0, stream>>>(F, P, E);
  scan_p3<<<BB*NCHUNK*(DIMV/16), 256, 0, stream>>>(dtb, bcb, A_log, E, xch, xcl, xz, Dp, yh, yl);
  wsplit<<<1024, 256, 0, stream>>>(W_out, Woh, Wol, (DIMV*INNERV)/4);
  gemm_bf16s<2><<<dim3(DIMV/64, MMV/128), 256, 0, stream>>>(yh, yl, Woh, Wol, out, DIMV, x);
}

// Round 5
// 287.324 us; speedup vs baseline: 2.2076x; 1.2566x over previous
//
#include <hip/hip_runtime.h>
#include <math.h>

#define BB 2
#define LL 2048
#define DIMV 1024
#define SSV 16
#define INNERV 1024
#define E2V 2048
#define MMV (BB*LL)      // 4096 rows
#define NCHUNK 64
#define CLEN 32          // LL / NCHUNK

typedef __attribute__((ext_vector_type(8))) short short8;   // 8 bf16 = 4 VGPRs (MFMA A/B frag)
typedef __attribute__((ext_vector_type(4))) float f32x4;    // MFMA C/D frag

static __device__ __forceinline__ float4 ld4(const float* p){
  return *reinterpret_cast<const float4*>(p);
}
// RNE fp32 -> bf16 (bit-level)
static __device__ __forceinline__ ushort f2bf(float x){
  unsigned u = __float_as_uint(x);
  unsigned r = (u + 0x7fffu + ((u >> 16) & 1u)) >> 16;
  return (ushort)r;
}
static __device__ __forceinline__ float bf2f(ushort h){
  return __uint_as_float(((unsigned)h) << 16);
}
static __device__ __forceinline__ void split1(float x, ushort& h, ushort& l){
  h = f2bf(x);
  l = f2bf(x - bf2f(h));
}
// async global->LDS, 16B per lane; lds dest wave-uniform base + lane*16
static __device__ __forceinline__ void gld16(const void* g, void* l){
  __builtin_amdgcn_global_load_lds(
      (const __attribute__((address_space(1))) void*)g,
      (__attribute__((address_space(3))) void*)l, 16, 0, 0);
}

// ---------------- LayerNorm -> split bf16 hi/lo ----------------
__global__ __launch_bounds__(256) void ln_kernel(const float* __restrict__ x,
        const float* __restrict__ gamma, const float* __restrict__ beta,
        ushort* __restrict__ hh, ushort* __restrict__ hl){
  int row = blockIdx.x;
  int tid = threadIdx.x;
  const float* xr = x + (size_t)row*DIMV;
  float4 v = ld4(xr + tid*4);
  float s  = v.x+v.y+v.z+v.w;
  float s2 = v.x*v.x+v.y*v.y+v.z*v.z+v.w*v.w;
  for (int o=32;o;o>>=1){ s += __shfl_down(s,o); s2 += __shfl_down(s2,o); }
  __shared__ float red[8];
  int wid = tid>>6, lane = tid&63;
  if (lane==0){ red[wid]=s; red[4+wid]=s2; }
  __syncthreads();
  s  = red[0]+red[1]+red[2]+red[3];
  s2 = red[4]+red[5]+red[6]+red[7];
  float mu  = s*(1.f/DIMV);
  float var = s2*(1.f/DIMV) - mu*mu;
  float rstd = rsqrtf(var + 1e-5f);
  float4 g = ld4(gamma + tid*4), be = ld4(beta + tid*4);
  float o0 = (v.x-mu)*rstd*g.x + be.x;
  float o1 = (v.y-mu)*rstd*g.y + be.y;
  float o2 = (v.z-mu)*rstd*g.z + be.z;
  float o3 = (v.w-mu)*rstd*g.w + be.w;
  ushort4 H, L;
  split1(o0,H.x,L.x); split1(o1,H.y,L.y); split1(o2,H.z,L.z); split1(o3,H.w,L.w);
  *reinterpret_cast<ushort4*>(hh + (size_t)row*DIMV + tid*4) = H;
  *reinterpret_cast<ushort4*>(hl + (size_t)row*DIMV + tid*4) = L;
}

// ---------------- weight split: fp32[n] -> bf16 hi/lo ----------------
__global__ __launch_bounds__(256) void wsplit(const float* __restrict__ src,
        ushort* __restrict__ hi, ushort* __restrict__ lo, int n4){
  int i = blockIdx.x*256 + threadIdx.x;
  if (i >= n4) return;
  float4 v = ld4(src + (size_t)i*4);
  ushort4 H, L;
  split1(v.x,H.x,L.x); split1(v.y,H.y,L.y); split1(v.z,H.z,L.z); split1(v.w,H.w,L.w);
  *reinterpret_cast<ushort4*>(hi + (size_t)i*4) = H;
  *reinterpret_cast<ushort4*>(lo + (size_t)i*4) = L;
}

// ============ split-bf16 MFMA GEMM: Co[M,N] = A[M,1024]*Bw[N,1024]^T ============
// m97-canonical 2-barrier-per-K-step, SINGLE LDS buffer (race-proof template).
// BM=128, BN=64, BK=32, 256 thr (2m x 2n waves; wave tile 64x32).
#define GBK 32
#define NKT 32

template<int EPI>
__global__ __launch_bounds__(256) void gemm_bf16s(
    const ushort* __restrict__ Ah, const ushort* __restrict__ Al,
    const ushort* __restrict__ Bh, const ushort* __restrict__ Bl,
    float* __restrict__ Co, int N, const float* __restrict__ aux){
  __shared__ __align__(16) ushort lds[12288];   // 24KB single buffer
  const int t  = threadIdx.x;
  const int bm = blockIdx.y * 128, bn = blockIdx.x * 64;

  const int r4 = t >> 2;
  const int k16 = (t & 3) ^ (r4 & 3);
  const ushort* gAh = Ah + (size_t)(bm + r4)*1024 + k16*8;
  const ushort* gAl = Al + (size_t)(bm + r4)*1024 + k16*8;
  const ushort* gBh = Bh + (size_t)(bn + r4)*1024 + k16*8;
  const ushort* gBl = Bl + (size_t)(bn + r4)*1024 + k16*8;
  const int wofs = (t >> 6) * 1024;

  const int l  = t & 63, wv = t >> 6;
  const int wm = wv & 1, wn = wv >> 1;
  const int fr = l & 15, kb = l >> 4;
  const int sw = (kb ^ (fr & 3)) * 16;
  const int aofs = (wm*64 + fr)*64 + sw;
  const int bofs = (wn*32 + fr)*64 + sw;

  f32x4 acc[4][2];
  #pragma unroll
  for (int m=0;m<4;m++){
    #pragma unroll
    for (int n=0;n<2;n++) acc[m][n] = (f32x4){0.f,0.f,0.f,0.f};
  }

  char* Lb = (char*)lds;
  for (int kt = 0; kt < NKT; ++kt){
    const int ko = kt*GBK;
    gld16(gAh + ko,           Lb +     0 + wofs);
    gld16(gAh + ko + 64*1024, Lb +  4096 + wofs);
    gld16(gAl + ko,           Lb +  8192 + wofs);
    gld16(gAl + ko + 64*1024, Lb + 12288 + wofs);
    gld16(gBh + ko,           Lb + 16384 + wofs);
    gld16(gBl + ko,           Lb + 20480 + wofs);
    __syncthreads();
    short8 ah[4], al[4], bh[2], bl[2];
    #pragma unroll
    for (int m=0;m<4;m++){
      ah[m] = *(const short8*)(Lb +        aofs + m*1024);
      al[m] = *(const short8*)(Lb + 8192 + aofs + m*1024);
    }
    #pragma unroll
    for (int n=0;n<2;n++){
      bh[n] = *(const short8*)(Lb + 16384 + bofs + n*1024);
      bl[n] = *(const short8*)(Lb + 20480 + bofs + n*1024);
    }
    #pragma unroll
    for (int m=0;m<4;m++){
      #pragma unroll
      for (int n=0;n<2;n++){
        acc[m][n] = __builtin_amdgcn_mfma_f32_16x16x32_bf16(ah[m], bh[n], acc[m][n], 0,0,0);
        acc[m][n] = __builtin_amdgcn_mfma_f32_16x16x32_bf16(al[m], bh[n], acc[m][n], 0,0,0);
        acc[m][n] = __builtin_amdgcn_mfma_f32_16x16x32_bf16(ah[m], bl[n], acc[m][n], 0,0,0);
      }
    }
    __syncthreads();
  }

  #pragma unroll
  for (int m=0;m<4;m++){
    int row0 = bm + wm*64 + m*16 + kb*4;
    #pragma unroll
    for (int n=0;n<2;n++){
      int col = bn + wn*32 + n*16 + fr;
      #pragma unroll
      for (int j=0;j<4;j++){
        int r = row0 + j;
        float v = acc[m][n][j];
        if (EPI==1){ v += aux[col]; v = (v > 20.f) ? v : log1pf(__expf(v)); }
        if (EPI==2){ v += aux[(size_t)r*N + col]; }
        Co[(size_t)r*N + col] = v;
      }
    }
  }
}

// ---------------- depthwise conv(K=3,pad=1) + silu -> bf16 hi/lo ----------------
__global__ __launch_bounds__(256) void conv_silu_kernel(const float* __restrict__ xz,
        const float* __restrict__ cw, ushort* __restrict__ xch, ushort* __restrict__ xcl){
  int idx = blockIdx.x*256 + threadIdx.x;
  int d4  = idx & 255;
  int row = idx >> 8;
  int t = row & (LL-1);
  const float* p = xz + (size_t)row*E2V + d4*4;
  float4 x1 = ld4(p);
  float4 x0 = (t>0)    ? ld4(p - E2V) : make_float4(0.f,0.f,0.f,0.f);
  float4 x2 = (t<LL-1) ? ld4(p + E2V) : make_float4(0.f,0.f,0.f,0.f);
  int d = d4*4;
  float w[12];
  #pragma unroll
  for (int i=0;i<12;i++) w[i] = cw[d*3 + i];
  float4 o;
  o.x = x0.x*w[0] + x1.x*w[1]  + x2.x*w[2];
  o.y = x0.y*w[3] + x1.y*w[4]  + x2.y*w[5];
  o.z = x0.z*w[6] + x1.z*w[7]  + x2.z*w[8];
  o.w = x0.w*w[9] + x1.w*w[10] + x2.w*w[11];
  o.x = o.x / (1.f + __expf(-o.x));
  o.y = o.y / (1.f + __expf(-o.y));
  o.z = o.z / (1.f + __expf(-o.z));
  o.w = o.w / (1.f + __expf(-o.w));
  ushort4 H, L;
  split1(o.x,H.x,L.x); split1(o.y,H.y,L.y); split1(o.z,H.z,L.z); split1(o.w,H.w,L.w);
  *reinterpret_cast<ushort4*>(xch + (size_t)row*DIMV + d4*4) = H;
  *reinterpret_cast<ushort4*>(xcl + (size_t)row*DIMV + d4*4) = L;
}

// ---------------- W_x transpose (32x1024 -> 1024x32) ----------------
__global__ __launch_bounds__(256) void transpose_wx_kernel(const float* __restrict__ wx,
        float* __restrict__ wxt){
  int idx = blockIdx.x*256 + threadIdx.x;
  int e = idx >> 10, k = idx & 1023;
  wxt[k*32 + e] = wx[idx];
}

// ---------------- BC = xc @ W_x^T  (N=32), xc reconstructed hi+lo ----------------
__global__ __launch_bounds__(256) void bc_kernel(const ushort* __restrict__ xch,
        const ushort* __restrict__ xcl, const float* __restrict__ wxt,
        float* __restrict__ bc){
  __shared__ ushort sh[8192], sl[8192];
  int tid = threadIdx.x;
  int row0 = blockIdx.x * 8;
  const ushort4* srcH = (const ushort4*)(xch + (size_t)row0*DIMV);
  const ushort4* srcL = (const ushort4*)(xcl + (size_t)row0*DIMV);
  #pragma unroll
  for (int i=0;i<8;i++){
    ((ushort4*)sh)[tid + i*256] = srcH[tid + i*256];
    ((ushort4*)sl)[tid + i*256] = srcL[tid + i*256];
  }
  __syncthreads();
  int r = tid >> 5, e = tid & 31;
  float acc = 0.f;
  for (int k=0;k<1024;k++){
    float xv = bf2f(sh[r*1024+k]) + bf2f(sl[r*1024+k]);
    acc = fmaf(xv, wxt[k*32+e], acc);
  }
  bc[(size_t)(row0 + r)*32 + e] = acc;
}

// ======== scan, one thread per channel d; S=16 state in registers ========
// pass 1: per-chunk local final-state F[.,s] and log-product via sum(dt):
//   P[.,s] = exp(sum_t dt * a_s)
__global__ __launch_bounds__(256) void scan_p1(const float* __restrict__ dt,
        const float* __restrict__ bc, const float* __restrict__ A_log,
        float* __restrict__ F, float* __restrict__ P){
  __shared__ float sB[CLEN*32];
  int bid = blockIdx.x;                 // b*(NCHUNK*4) + c*4 + dblk
  int dblk = bid & 3;
  int c  = (bid >> 2) & (NCHUNK-1);
  int b  = bid >> 8;
  int tid = threadIdx.x;
  int d = dblk*256 + tid;
  int row0 = b*LL + c*CLEN;
  ((float4*)sB)[tid] = *((const float4*)(bc + (size_t)row0*32) + tid);
  float a[16];
  {
    const float4* ap = (const float4*)(A_log + d*16);
    #pragma unroll
    for (int q=0;q<4;q++){
      float4 v = ap[q];
      a[q*4+0]=-__expf(v.x); a[q*4+1]=-__expf(v.y);
      a[q*4+2]=-__expf(v.z); a[q*4+3]=-__expf(v.w);
    }
  }
  __syncthreads();
  float st[16];
  #pragma unroll
  for (int s=0;s<16;s++) st[s]=0.f;
  float sdt = 0.f;
  const float* dtp = dt + (size_t)row0*DIMV + d;
  for (int t=0;t<CLEN;t++){
    float dtv = dtp[(size_t)t*DIMV];
    sdt += dtv;
    float4 B0 = *(const float4*)&sB[t*32+0];
    float4 B1 = *(const float4*)&sB[t*32+4];
    float4 B2 = *(const float4*)&sB[t*32+8];
    float4 B3 = *(const float4*)&sB[t*32+12];
    float Bv[16] = {B0.x,B0.y,B0.z,B0.w,B1.x,B1.y,B1.z,B1.w,
                    B2.x,B2.y,B2.z,B2.w,B3.x,B3.y,B3.z,B3.w};
    #pragma unroll
    for (int s=0;s<16;s++){
      float dA = __expf(dtv*a[s]);
      st[s] = fmaf(st[s], dA, dtv*Bv[s]);
    }
  }
  size_t o = ((size_t)((b*NCHUNK + c)*DIMV + d))*16;
  #pragma unroll
  for (int q=0;q<4;q++){
    *(float4*)(F + o + q*4) = make_float4(st[q*4],st[q*4+1],st[q*4+2],st[q*4+3]);
    *(float4*)(P + o + q*4) = make_float4(__expf(sdt*a[q*4]),  __expf(sdt*a[q*4+1]),
                                          __expf(sdt*a[q*4+2]),__expf(sdt*a[q*4+3]));
  }
}

// pass 2: serial combine over chunks -> entry state E per chunk
__global__ __launch_bounds__(256) void scan_p2(const float* __restrict__ F,
        const float* __restrict__ P, float* __restrict__ E){
  int idx = blockIdx.x*256 + threadIdx.x;   // BB*DIMV*SSV = 32768
  int b  = idx >> 14;
  int ds = idx & 16383;
  float e = 0.f;
  for (int c=0;c<NCHUNK;c++){
    size_t o = ((size_t)(b*NCHUNK + c) << 14) + ds;
    E[o] = e;
    e = fmaf(P[o], e, F[o]);
  }
}

// pass 3: replay with true entry state; fuse y = sum_s st*C + D*xc, *silu(z)
__global__ __launch_bounds__(256) void scan_p3(const float* __restrict__ dt,
        const float* __restrict__ bc, const float* __restrict__ A_log,
        const float* __restrict__ E, const ushort* __restrict__ xch,
        const ushort* __restrict__ xcl, const float* __restrict__ xz,
        const float* __restrict__ Dp,
        ushort* __restrict__ yh, ushort* __restrict__ yl){
  __shared__ float sBC[CLEN*32];
  int bid = blockIdx.x;
  int dblk = bid & 3;
  int c  = (bid >> 2) & (NCHUNK-1);
  int b  = bid >> 8;
  int tid = threadIdx.x;
  int d = dblk*256 + tid;
  int row0 = b*LL + c*CLEN;
  ((float4*)sBC)[tid] = *((const float4*)(bc + (size_t)row0*32) + tid);
  float a[16];
  {
    const float4* ap = (const float4*)(A_log + d*16);
    #pragma unroll
    for (int q=0;q<4;q++){
      float4 v = ap[q];
      a[q*4+0]=-__expf(v.x); a[q*4+1]=-__expf(v.y);
      a[q*4+2]=-__expf(v.z); a[q*4+3]=-__expf(v.w);
    }
  }
  float st[16];
  {
    size_t o = ((size_t)((b*NCHUNK + c)*DIMV + d))*16;
    #pragma unroll
    for (int q=0;q<4;q++){
      float4 v = *(const float4*)(E + o + q*4);
      st[q*4]=v.x; st[q*4+1]=v.y; st[q*4+2]=v.z; st[q*4+3]=v.w;
    }
  }
  float Dv = Dp[d];
  __syncthreads();
  const float* dtp = dt + (size_t)row0*DIMV + d;
  for (int t=0;t<CLEN;t++){
    float dtv = dtp[(size_t)t*DIMV];
    float4 B0 = *(const float4*)&sBC[t*32+0];
    float4 B1 = *(const float4*)&sBC[t*32+4];
    float4 B2 = *(const float4*)&sBC[t*32+8];
    float4 B3 = *(const float4*)&sBC[t*32+12];
    float4 C0 = *(const float4*)&sBC[t*32+16];
    float4 C1 = *(const float4*)&sBC[t*32+20];
    float4 C2 = *(const float4*)&sBC[t*32+24];
    float4 C3 = *(const float4*)&sBC[t*32+28];
    float Bv[16] = {B0.x,B0.y,B0.z,B0.w,B1.x,B1.y,B1.z,B1.w,
                    B2.x,B2.y,B2.z,B2.w,B3.x,B3.y,B3.z,B3.w};
    float Cv[16] = {C0.x,C0.y,C0.z,C0.w,C1.x,C1.y,C1.z,C1.w,
                    C2.x,C2.y,C2.z,C2.w,C3.x,C3.y,C3.z,C3.w};
    float y = 0.f;
    #pragma unroll
    for (int s=0;s<16;s++){
      float dA = __expf(dtv*a[s]);
      st[s] = fmaf(st[s], dA, dtv*Bv[s]);
      y = fmaf(st[s], Cv[s], y);
    }
    int row = row0 + t;
    size_t ofs = (size_t)row*DIMV + d;
    float xcv = bf2f(xch[ofs]) + bf2f(xcl[ofs]);
    float zv  = xz[(size_t)row*E2V + INNERV + d];
    float sz  = zv / (1.f + __expf(-zv));
    float yv = (y + Dv*xcv)*sz;
    ushort H, L; split1(yv, H, L);
    yh[ofs] = H;
    yl[ofs] = L;
  }
}

extern "C" void kernel_launch(void* const* d_in, const int* in_sizes, int n_in,
                              void* d_out, int out_size, void* d_ws, size_t ws_size,
                              hipStream_t stream){
  const float* x     = (const float*)d_in[0];
  const float* gamma = (const float*)d_in[1];
  const float* beta  = (const float*)d_in[2];
  const float* W_in  = (const float*)d_in[3];
  const float* cw    = (const float*)d_in[4];
  const float* W_x   = (const float*)d_in[5];
  const float* W_dt  = (const float*)d_in[6];
  const float* b_dt  = (const float*)d_in[7];
  const float* A_log = (const float*)d_in[8];
  const float* Dp    = (const float*)d_in[9];
  const float* W_out = (const float*)d_in[10];
  float* out = (float*)d_out;
  float* ws  = (float*)d_ws;
  const size_t MB = (size_t)1 << 20;   // 1M floats
  // layout (float units), max 23M+288K floats ~= 93MB (<= proven-safe ~97MB)
  float*  xz  = ws;                               // [0,8M)
  ushort* hh  = (ushort*)(ws + 8*MB);             // [8M,10M)   h hi; dead after gemm0
  ushort* hl  = (ushort*)(ws + 10*MB);            // [10M,12M)  h lo; dead after gemm0
  float*  F   = ws + 8*MB;                        // [8M,10M)   after hh dead; dead after p2
  float*  P   = ws + 10*MB;                       // [10M,12M)  after hl dead; dead after p2
  ushort* yh  = (ushort*)(ws + 8*MB);             // [8M,10M)   p3 writes (F dead)
  ushort* yl  = (ushort*)(ws + 10*MB);            // [10M,12M)
  ushort* xch = (ushort*)(ws + 12*MB);            // [12M,14M)  dead after p3
  ushort* xcl = (ushort*)(ws + 14*MB);            // [14M,16M)  dead after p3
  ushort* Woh = (ushort*)(ws + 12*MB);            // [12M,12.5M) written AFTER p3
  ushort* Wol = (ushort*)(ws + 12*MB + 512*1024); // [12.5M,13M)
  float*  dtb = ws + 16*MB;                       // [16M,20M)
  ushort* Wih = (ushort*)(ws + 20*MB);            // [20M,21M)  dead after gemm0
  ushort* Wil = (ushort*)(ws + 21*MB);            // [21M,22M)  dead after gemm0
  float*  E   = ws + 20*MB;                       // [20M,22M)  p2 writes (Wih dead)
  ushort* Wdh = (ushort*)(ws + 22*MB);            // [22M,22.5M) dead after gemm1
  ushort* Wdl = (ushort*)(ws + 22*MB + 512*1024); // [22.5M,23M)
  float*  bcb = ws + 23*MB;                       // 128K floats
  float*  wxt = ws + 23*MB + 256*1024;            // 32K floats

  wsplit<<<2048, 256, 0, stream>>>(W_in,  Wih, Wil, (2*INNERV*DIMV)/4);
  wsplit<<<1024, 256, 0, stream>>>(W_dt,  Wdh, Wdl, (INNERV*DIMV)/4);
  transpose_wx_kernel<<<(32*1024)/256, 256, 0, stream>>>(W_x, wxt);

  ln_kernel<<<MMV, 256, 0, stream>>>(x, gamma, beta, hh, hl);
  gemm_bf16s<0><<<dim3(E2V/64, MMV/128), 256, 0, stream>>>(hh, hl, Wih, Wil, xz, E2V, nullptr);
  conv_silu_kernel<<<(MMV*(DIMV/4))/256, 256, 0, stream>>>(xz, cw, xch, xcl);
  gemm_bf16s<1><<<dim3(INNERV/64, MMV/128), 256, 0, stream>>>(xch, xcl, Wdh, Wdl, dtb, INNERV, b_dt);
  bc_kernel<<<MMV/8, 256, 0, stream>>>(xch, xcl, wxt, bcb);
  scan_p1<<<BB*NCHUNK*(DIMV/256), 256, 0, stream>>>(dtb, bcb, A_log, F, P);
  scan_p2<<<(BB*DIMV*SSV)/256, 256, 0, stream>>>(F, P, E);
  scan_p3<<<BB*NCHUNK*(DIMV/256), 256, 0, stream>>>(dtb, bcb, A_log, E, xch, xcl, xz, Dp, yh, yl);
  wsplit<<<1024, 256, 0, stream>>>(W_out, Woh, Wol, (DIMV*INNERV)/4);
  gemm_bf16s<2><<<dim3(DIMV/64, MMV/128), 256, 0, stream>>>(yh, yl, Woh, Wol, out, DIMV, x);
}

// Round 8
// 208.501 us; speedup vs baseline: 3.0421x; 1.3780x over previous
//
#include <hip/hip_runtime.h>
#include <math.h>

#define BB 2
#define LL 2048
#define DIMV 1024
#define SSV 16
#define INNERV 1024
#define E2V 2048
#define MMV (BB*LL)      // 4096 rows
#define NCHUNK 64
#define CLEN 32          // LL / NCHUNK

typedef __attribute__((ext_vector_type(8))) short short8;   // 8 bf16 = 4 VGPRs (MFMA A/B frag)
typedef __attribute__((ext_vector_type(4))) float f32x4;    // MFMA C/D frag

static __device__ __forceinline__ float4 ld4(const float* p){
  return *reinterpret_cast<const float4*>(p);
}
// RNE fp32 -> bf16 (bit-level)
static __device__ __forceinline__ ushort f2bf(float x){
  unsigned u = __float_as_uint(x);
  unsigned r = (u + 0x7fffu + ((u >> 16) & 1u)) >> 16;
  return (ushort)r;
}
static __device__ __forceinline__ float bf2f(ushort h){
  return __uint_as_float(((unsigned)h) << 16);
}
// async global->LDS, 16B per lane; lds dest wave-uniform base + lane*16
static __device__ __forceinline__ void gld16(const void* g, void* l){
  __builtin_amdgcn_global_load_lds(
      (const __attribute__((address_space(1))) void*)g,
      (__attribute__((address_space(3))) void*)l, 16, 0, 0);
}

// ---------------- LayerNorm -> bf16 ----------------
__global__ __launch_bounds__(256) void ln_kernel(const float* __restrict__ x,
        const float* __restrict__ gamma, const float* __restrict__ beta,
        ushort* __restrict__ hh){
  int row = blockIdx.x;
  int tid = threadIdx.x;
  const float* xr = x + (size_t)row*DIMV;
  float4 v = ld4(xr + tid*4);
  float s  = v.x+v.y+v.z+v.w;
  float s2 = v.x*v.x+v.y*v.y+v.z*v.z+v.w*v.w;
  for (int o=32;o;o>>=1){ s += __shfl_down(s,o); s2 += __shfl_down(s2,o); }
  __shared__ float red[8];
  int wid = tid>>6, lane = tid&63;
  if (lane==0){ red[wid]=s; red[4+wid]=s2; }
  __syncthreads();
  s  = red[0]+red[1]+red[2]+red[3];
  s2 = red[4]+red[5]+red[6]+red[7];
  float mu  = s*(1.f/DIMV);
  float var = s2*(1.f/DIMV) - mu*mu;
  float rstd = rsqrtf(var + 1e-5f);
  float4 g = ld4(gamma + tid*4), be = ld4(beta + tid*4);
  ushort4 H;
  H.x = f2bf((v.x-mu)*rstd*g.x + be.x);
  H.y = f2bf((v.y-mu)*rstd*g.y + be.y);
  H.z = f2bf((v.z-mu)*rstd*g.z + be.z);
  H.w = f2bf((v.w-mu)*rstd*g.w + be.w);
  *reinterpret_cast<ushort4*>(hh + (size_t)row*DIMV + tid*4) = H;
}

// ---------------- weight cast: fp32[n] -> bf16 ----------------
__global__ __launch_bounds__(256) void wcast(const float* __restrict__ src,
        ushort* __restrict__ hi, int n4){
  int i = blockIdx.x*256 + threadIdx.x;
  if (i >= n4) return;
  float4 v = ld4(src + (size_t)i*4);
  ushort4 H;
  H.x=f2bf(v.x); H.y=f2bf(v.y); H.z=f2bf(v.z); H.w=f2bf(v.w);
  *reinterpret_cast<ushort4*>(hi + (size_t)i*4) = H;
}

// ============ bf16 MFMA GEMM: Co[M,N] = A[M,1024]*Bw[N,1024]^T ============
// m97-canonical 2-barrier-per-K-step, SINGLE LDS buffer.
// BM=128, BN in {64,128}, BK=32, 256 thr (2m x 2n waves).
// 16B-unit XOR swizzle: physical slot p holds logical unit p^(row&3);
// staged via inverse-swizzled global src, read with the same XOR.
#define GBK 32
#define NKT 32

template<int EPI, int BN>
__global__ __launch_bounds__(256) void gemm_bf16(
    const ushort* __restrict__ A, const ushort* __restrict__ Bw,
    float* __restrict__ Co, int N, const float* __restrict__ aux){
  __shared__ __align__(16) ushort lds[(128+BN)*GBK];   // 12KB or 16KB
  const int t  = threadIdx.x;
  const int bm = blockIdx.y * 128, bn = blockIdx.x * BN;

  // staging addressing (inverse-swizzled global source)
  const int r4 = t >> 2;
  const int k16 = (t & 3) ^ (r4 & 3);
  const ushort* gA = A  + (size_t)(bm + r4)*1024 + k16*8;
  const ushort* gB = Bw + (size_t)(bn + r4)*1024 + k16*8;
  const int wofs = (t >> 6) * 1024;   // per-wave byte offset inside a 4KB segment

  // fragment read addressing (same XOR)
  const int l  = t & 63, wv = t >> 6;
  const int wm = wv & 1, wn = wv >> 1;
  const int fr = l & 15, kb = l >> 4;
  const int sw = (kb ^ (fr & 3)) * 16;
  const int WN = BN/2;                       // wave col-tile (64 or 32)
  const int NF = BN/64;                      // B frags per wave / 2
  const int aofs = (wm*64 + fr)*64 + sw;     // A region, row stride 64B
  const int bofs = 8192 + (wn*WN + fr)*64 + sw;  // B region at byte 8192

  f32x4 acc[4][2*NF];
  #pragma unroll
  for (int m=0;m<4;m++){
    #pragma unroll
    for (int n=0;n<2*NF;n++) acc[m][n] = (f32x4){0.f,0.f,0.f,0.f};
  }

  char* Lb = (char*)lds;
  for (int kt = 0; kt < NKT; ++kt){
    const int ko = kt*GBK;
    gld16(gA + ko,           Lb +    0 + wofs);
    gld16(gA + ko + 64*1024, Lb + 4096 + wofs);
    gld16(gB + ko,           Lb + 8192 + wofs);
    if (BN == 128) gld16(gB + ko + 64*1024, Lb + 12288 + wofs);
    __syncthreads();
    short8 a[4], b[2*NF];
    #pragma unroll
    for (int m=0;m<4;m++) a[m] = *(const short8*)(Lb + aofs + m*1024);
    #pragma unroll
    for (int n=0;n<2*NF;n++) b[n] = *(const short8*)(Lb + bofs + n*1024);
    #pragma unroll
    for (int m=0;m<4;m++){
      #pragma unroll
      for (int n=0;n<2*NF;n++)
        acc[m][n] = __builtin_amdgcn_mfma_f32_16x16x32_bf16(a[m], b[n], acc[m][n], 0,0,0);
    }
    __syncthreads();
  }

  // C/D layout: col = lane&15, row = (lane>>4)*4 + reg   [m89-verified]
  #pragma unroll
  for (int m=0;m<4;m++){
    int row0 = bm + wm*64 + m*16 + kb*4;
    #pragma unroll
    for (int n=0;n<2*NF;n++){
      int col = bn + wn*WN + n*16 + fr;
      #pragma unroll
      for (int j=0;j<4;j++){
        int r = row0 + j;
        float v = acc[m][n][j];
        if (EPI==1){ v += aux[col]; v = (v > 20.f) ? v : log1pf(__expf(v)); }
        if (EPI==2){ v += aux[(size_t)r*N + col]; }
        Co[(size_t)r*N + col] = v;
      }
    }
  }
}

// ---------------- depthwise conv(K=3,pad=1) + silu -> bf16 ----------------
__global__ __launch_bounds__(256) void conv_silu_kernel(const float* __restrict__ xz,
        const float* __restrict__ cw, ushort* __restrict__ xch){
  int idx = blockIdx.x*256 + threadIdx.x;
  int d4  = idx & 255;
  int row = idx >> 8;
  int t = row & (LL-1);
  const float* p = xz + (size_t)row*E2V + d4*4;
  float4 x1 = ld4(p);
  float4 x0 = (t>0)    ? ld4(p - E2V) : make_float4(0.f,0.f,0.f,0.f);
  float4 x2 = (t<LL-1) ? ld4(p + E2V) : make_float4(0.f,0.f,0.f,0.f);
  int d = d4*4;
  float w[12];
  #pragma unroll
  for (int i=0;i<12;i++) w[i] = cw[d*3 + i];
  float4 o;
  o.x = x0.x*w[0] + x1.x*w[1]  + x2.x*w[2];
  o.y = x0.y*w[3] + x1.y*w[4]  + x2.y*w[5];
  o.z = x0.z*w[6] + x1.z*w[7]  + x2.z*w[8];
  o.w = x0.w*w[9] + x1.w*w[10] + x2.w*w[11];
  o.x = o.x / (1.f + __expf(-o.x));
  o.y = o.y / (1.f + __expf(-o.y));
  o.z = o.z / (1.f + __expf(-o.z));
  o.w = o.w / (1.f + __expf(-o.w));
  ushort4 H;
  H.x=f2bf(o.x); H.y=f2bf(o.y); H.z=f2bf(o.z); H.w=f2bf(o.w);
  *reinterpret_cast<ushort4*>(xch + (size_t)row*DIMV + d4*4) = H;
}

// ---------------- W_x transpose (32x1024 -> 1024x32) ----------------
__global__ __launch_bounds__(256) void transpose_wx_kernel(const float* __restrict__ wx,
        float* __restrict__ wxt){
  int idx = blockIdx.x*256 + threadIdx.x;
  int e = idx >> 10, k = idx & 1023;
  wxt[k*32 + e] = wx[idx];
}

// ---------------- BC = xc @ W_x^T  (N=32) ----------------
__global__ __launch_bounds__(256) void bc_kernel(const ushort* __restrict__ xch,
        const float* __restrict__ wxt, float* __restrict__ bc){
  __shared__ ushort sh[8192];
  int tid = threadIdx.x;
  int row0 = blockIdx.x * 8;
  const ushort4* srcH = (const ushort4*)(xch + (size_t)row0*DIMV);
  #pragma unroll
  for (int i=0;i<8;i++)
    ((ushort4*)sh)[tid + i*256] = srcH[tid + i*256];
  __syncthreads();
  int r = tid >> 5, e = tid & 31;
  float acc = 0.f;
  for (int k=0;k<1024;k++){
    acc = fmaf(bf2f(sh[r*1024+k]), wxt[k*32+e], acc);
  }
  bc[(size_t)(row0 + r)*32 + e] = acc;
}

// ======== scan, one thread per channel d; S=16 state in registers ========
__global__ __launch_bounds__(256) void scan_p1(const float* __restrict__ dt,
        const float* __restrict__ bc, const float* __restrict__ A_log,
        float* __restrict__ F, float* __restrict__ P){
  __shared__ float sB[CLEN*32];
  int bid = blockIdx.x;                 // b*(NCHUNK*4) + c*4 + dblk
  int dblk = bid & 3;
  int c  = (bid >> 2) & (NCHUNK-1);
  int b  = bid >> 8;
  int tid = threadIdx.x;
  int d = dblk*256 + tid;
  int row0 = b*LL + c*CLEN;
  ((float4*)sB)[tid] = *((const float4*)(bc + (size_t)row0*32) + tid);
  float a[16];
  {
    const float4* ap = (const float4*)(A_log + d*16);
    #pragma unroll
    for (int q=0;q<4;q++){
      float4 v = ap[q];
      a[q*4+0]=-__expf(v.x); a[q*4+1]=-__expf(v.y);
      a[q*4+2]=-__expf(v.z); a[q*4+3]=-__expf(v.w);
    }
  }
  __syncthreads();
  float st[16];
  #pragma unroll
  for (int s=0;s<16;s++) st[s]=0.f;
  float sdt = 0.f;
  const float* dtp = dt + (size_t)row0*DIMV + d;
  for (int t=0;t<CLEN;t++){
    float dtv = dtp[(size_t)t*DIMV];
    sdt += dtv;
    float4 B0 = *(const float4*)&sB[t*32+0];
    float4 B1 = *(const float4*)&sB[t*32+4];
    float4 B2 = *(const float4*)&sB[t*32+8];
    float4 B3 = *(const float4*)&sB[t*32+12];
    float Bv[16] = {B0.x,B0.y,B0.z,B0.w,B1.x,B1.y,B1.z,B1.w,
                    B2.x,B2.y,B2.z,B2.w,B3.x,B3.y,B3.z,B3.w};
    #pragma unroll
    for (int s=0;s<16;s++){
      float dA = __expf(dtv*a[s]);
      st[s] = fmaf(st[s], dA, dtv*Bv[s]);
    }
  }
  size_t o = ((size_t)((b*NCHUNK + c)*DIMV + d))*16;
  #pragma unroll
  for (int q=0;q<4;q++){
    *(float4*)(F + o + q*4) = make_float4(st[q*4],st[q*4+1],st[q*4+2],st[q*4+3]);
    *(float4*)(P + o + q*4) = make_float4(__expf(sdt*a[q*4]),  __expf(sdt*a[q*4+1]),
                                          __expf(sdt*a[q*4+2]),__expf(sdt*a[q*4+3]));
  }
}

__global__ __launch_bounds__(256) void scan_p2(const float* __restrict__ F,
        const float* __restrict__ P, float* __restrict__ E){
  int idx = blockIdx.x*256 + threadIdx.x;   // BB*DIMV*SSV = 32768
  int b  = idx >> 14;
  int ds = idx & 16383;
  float e = 0.f;
  for (int c=0;c<NCHUNK;c++){
    size_t o = ((size_t)(b*NCHUNK + c) << 14) + ds;
    E[o] = e;
    e = fmaf(P[o], e, F[o]);
  }
}

__global__ __launch_bounds__(256) void scan_p3(const float* __restrict__ dt,
        const float* __restrict__ bc, const float* __restrict__ A_log,
        const float* __restrict__ E, const ushort* __restrict__ xch,
        const float* __restrict__ xz, const float* __restrict__ Dp,
        ushort* __restrict__ yh){
  __shared__ float sBC[CLEN*32];
  int bid = blockIdx.x;
  int dblk = bid & 3;
  int c  = (bid >> 2) & (NCHUNK-1);
  int b  = bid >> 8;
  int tid = threadIdx.x;
  int d = dblk*256 + tid;
  int row0 = b*LL + c*CLEN;
  ((float4*)sBC)[tid] = *((const float4*)(bc + (size_t)row0*32) + tid);
  float a[16];
  {
    const float4* ap = (const float4*)(A_log + d*16);
    #pragma unroll
    for (int q=0;q<4;q++){
      float4 v = ap[q];
      a[q*4+0]=-__expf(v.x); a[q*4+1]=-__expf(v.y);
      a[q*4+2]=-__expf(v.z); a[q*4+3]=-__expf(v.w);
    }
  }
  float st[16];
  {
    size_t o = ((size_t)((b*NCHUNK + c)*DIMV + d))*16;
    #pragma unroll
    for (int q=0;q<4;q++){
      float4 v = *(const float4*)(E + o + q*4);
      st[q*4]=v.x; st[q*4+1]=v.y; st[q*4+2]=v.z; st[q*4+3]=v.w;
    }
  }
  float Dv = Dp[d];
  __syncthreads();
  const float* dtp = dt + (size_t)row0*DIMV + d;
  for (int t=0;t<CLEN;t++){
    float dtv = dtp[(size_t)t*DIMV];
    float4 B0 = *(const float4*)&sBC[t*32+0];
    float4 B1 = *(const float4*)&sBC[t*32+4];
    float4 B2 = *(const float4*)&sBC[t*32+8];
    float4 B3 = *(const float4*)&sBC[t*32+12];
    float4 C0 = *(const float4*)&sBC[t*32+16];
    float4 C1 = *(const float4*)&sBC[t*32+20];
    float4 C2 = *(const float4*)&sBC[t*32+24];
    float4 C3 = *(const float4*)&sBC[t*32+28];
    float Bv[16] = {B0.x,B0.y,B0.z,B0.w,B1.x,B1.y,B1.z,B1.w,
                    B2.x,B2.y,B2.z,B2.w,B3.x,B3.y,B3.z,B3.w};
    float Cv[16] = {C0.x,C0.y,C0.z,C0.w,C1.x,C1.y,C1.z,C1.w,
                    C2.x,C2.y,C2.z,C2.w,C3.x,C3.y,C3.z,C3.w};
    float y = 0.f;
    #pragma unroll
    for (int s=0;s<16;s++){
      float dA = __expf(dtv*a[s]);
      st[s] = fmaf(st[s], dA, dtv*Bv[s]);
      y = fmaf(st[s], Cv[s], y);
    }
    int row = row0 + t;
    size_t ofs = (size_t)row*DIMV + d;
    float xcv = bf2f(xch[ofs]);
    float zv  = xz[(size_t)row*E2V + INNERV + d];
    float sz  = zv / (1.f + __expf(-zv));
    yh[ofs] = f2bf((y + Dv*xcv)*sz);
  }
}

extern "C" void kernel_launch(void* const* d_in, const int* in_sizes, int n_in,
                              void* d_out, int out_size, void* d_ws, size_t ws_size,
                              hipStream_t stream){
  const float* x     = (const float*)d_in[0];
  const float* gamma = (const float*)d_in[1];
  const float* beta  = (const float*)d_in[2];
  const float* W_in  = (const float*)d_in[3];
  const float* cw    = (const float*)d_in[4];
  const float* W_x   = (const float*)d_in[5];
  const float* W_dt  = (const float*)d_in[6];
  const float* b_dt  = (const float*)d_in[7];
  const float* A_log = (const float*)d_in[8];
  const float* Dp    = (const float*)d_in[9];
  const float* W_out = (const float*)d_in[10];
  float* out = (float*)d_out;
  float* ws  = (float*)d_ws;
  const size_t MB = (size_t)1 << 20;   // 1M floats
  // layout (float units). NOTE sizes: bf16 buffers of 4M elems = 2M floats.
  float*  xz  = ws;                               // [0,8M)
  ushort* hh  = (ushort*)(ws + 8*MB);             // [8M,10M)  dead after gemm0
  ushort* yh  = (ushort*)(ws + 8*MB);             // [8M,10M)  p3 writes (hh dead)
  ushort* xch = (ushort*)(ws + 10*MB);            // [10M,12M) disjoint from yh
  float*  dtb = ws + 12*MB;                       // [12M,16M)
  float*  F   = ws + 16*MB;                       // [16M,18M)
  float*  P   = ws + 18*MB;                       // [18M,20M)
  float*  E   = ws + 20*MB;                       // [20M,22M)
  ushort* Wih = (ushort*)(ws + 22*MB);            // [22M,23M)  2M ushorts
  ushort* Wdh = (ushort*)(ws + 23*MB);            // [23M,23.5M)
  ushort* Woh = (ushort*)(ws + 23*MB + 512*1024); // [23.5M,24M)
  float*  bcb = ws + 24*MB;                       // 128K floats
  float*  wxt = ws + 24*MB + 256*1024;            // 32K floats

  wcast<<<2048, 256, 0, stream>>>(W_in,  Wih, (2*INNERV*DIMV)/4);
  wcast<<<1024, 256, 0, stream>>>(W_dt,  Wdh, (INNERV*DIMV)/4);
  wcast<<<1024, 256, 0, stream>>>(W_out, Woh, (DIMV*INNERV)/4);
  transpose_wx_kernel<<<(32*1024)/256, 256, 0, stream>>>(W_x, wxt);

  ln_kernel<<<MMV, 256, 0, stream>>>(x, gamma, beta, hh);
  gemm_bf16<0,128><<<dim3(E2V/128, MMV/128), 256, 0, stream>>>(hh, Wih, xz, E2V, nullptr);
  conv_silu_kernel<<<(MMV*(DIMV/4))/256, 256, 0, stream>>>(xz, cw, xch);
  gemm_bf16<1,64><<<dim3(INNERV/64, MMV/128), 256, 0, stream>>>(xch, Wdh, dtb, INNERV, b_dt);
  bc_kernel<<<MMV/8, 256, 0, stream>>>(xch, wxt, bcb);
  scan_p1<<<BB*NCHUNK*(DIMV/256), 256, 0, stream>>>(dtb, bcb, A_log, F, P);
  scan_p2<<<(BB*DIMV*SSV)/256, 256, 0, stream>>>(F, P, E);
  scan_p3<<<BB*NCHUNK*(DIMV/256), 256, 0, stream>>>(dtb, bcb, A_log, E, xch, xz, Dp, yh);
  gemm_bf16<2,64><<<dim3(DIMV/64, MMV/128), 256, 0, stream>>>(yh, Woh, out, DIMV, x);
}

// Round 9
// 195.115 us; speedup vs baseline: 3.2509x; 1.0686x over previous
//
#include <hip/hip_runtime.h>
#include <math.h>

#define BB 2
#define LL 2048
#define DIMV 1024
#define SSV 16
#define INNERV 1024
#define E2V 2048
#define MMV (BB*LL)      // 4096 rows
#define NCHUNK 64
#define CLEN 32          // LL / NCHUNK

typedef __attribute__((ext_vector_type(8))) short short8;   // 8 bf16 = 4 VGPRs (MFMA A/B frag)
typedef __attribute__((ext_vector_type(4))) float f32x4;    // MFMA C/D frag

static __device__ __forceinline__ float4 ld4(const float* p){
  return *reinterpret_cast<const float4*>(p);
}
// RNE fp32 -> bf16 (bit-level)
static __device__ __forceinline__ ushort f2bf(float x){
  unsigned u = __float_as_uint(x);
  unsigned r = (u + 0x7fffu + ((u >> 16) & 1u)) >> 16;
  return (ushort)r;
}
static __device__ __forceinline__ float bf2f(ushort h){
  return __uint_as_float(((unsigned)h) << 16);
}
// async global->LDS, 16B per lane; lds dest wave-uniform base + lane*16
static __device__ __forceinline__ void gld16(const void* g, void* l){
  __builtin_amdgcn_global_load_lds(
      (const __attribute__((address_space(1))) void*)g,
      (__attribute__((address_space(3))) void*)l, 16, 0, 0);
}

// ---------------- LayerNorm -> bf16 ----------------
__global__ __launch_bounds__(256) void ln_kernel(const float* __restrict__ x,
        const float* __restrict__ gamma, const float* __restrict__ beta,
        ushort* __restrict__ hh){
  int row = blockIdx.x;
  int tid = threadIdx.x;
  const float* xr = x + (size_t)row*DIMV;
  float4 v = ld4(xr + tid*4);
  float s  = v.x+v.y+v.z+v.w;
  float s2 = v.x*v.x+v.y*v.y+v.z*v.z+v.w*v.w;
  for (int o=32;o;o>>=1){ s += __shfl_down(s,o); s2 += __shfl_down(s2,o); }
  __shared__ float red[8];
  int wid = tid>>6, lane = tid&63;
  if (lane==0){ red[wid]=s; red[4+wid]=s2; }
  __syncthreads();
  s  = red[0]+red[1]+red[2]+red[3];
  s2 = red[4]+red[5]+red[6]+red[7];
  float mu  = s*(1.f/DIMV);
  float var = s2*(1.f/DIMV) - mu*mu;
  float rstd = rsqrtf(var + 1e-5f);
  float4 g = ld4(gamma + tid*4), be = ld4(beta + tid*4);
  ushort4 H;
  H.x = f2bf((v.x-mu)*rstd*g.x + be.x);
  H.y = f2bf((v.y-mu)*rstd*g.y + be.y);
  H.z = f2bf((v.z-mu)*rstd*g.z + be.z);
  H.w = f2bf((v.w-mu)*rstd*g.w + be.w);
  *reinterpret_cast<ushort4*>(hh + (size_t)row*DIMV + tid*4) = H;
}

// ------- combined init: cast W_in/W_dt/W_out to bf16 + transpose W_x -------
// regions (in thread idx): [0,512K) W_in f4 | [512K,768K) W_dt f4 |
// [768K,1024K) W_out f4 | [1024K,1024K+32768) W_x transpose (scalar)
__global__ __launch_bounds__(256) void init_kernel(
        const float* __restrict__ W_in, const float* __restrict__ W_dt,
        const float* __restrict__ W_out, const float* __restrict__ wx,
        ushort* __restrict__ Wih, ushort* __restrict__ Wdh,
        ushort* __restrict__ Woh, float* __restrict__ wxt){
  int idx = blockIdx.x*256 + threadIdx.x;
  if (idx < 1024*1024){
    const float* src; ushort* dst; int i;
    if (idx < 512*1024){ src = W_in;  dst = Wih; i = idx; }
    else if (idx < 768*1024){ src = W_dt;  dst = Wdh; i = idx - 512*1024; }
    else { src = W_out; dst = Woh; i = idx - 768*1024; }
    float4 v = ld4(src + (size_t)i*4);
    ushort4 H;
    H.x=f2bf(v.x); H.y=f2bf(v.y); H.z=f2bf(v.z); H.w=f2bf(v.w);
    *reinterpret_cast<ushort4*>(dst + (size_t)i*4) = H;
  } else {
    int j = idx - 1024*1024;           // [0, 32768)
    int e = j >> 10, k = j & 1023;
    wxt[k*32 + e] = wx[j];
  }
}

// ============ bf16 MFMA GEMM: Co[M,N] = A[M,1024]*Bw[N,1024]^T ============
// m97-canonical 2-barrier-per-K-step, SINGLE LDS buffer.
// BM=128, BN in {64,128}, BK=32, 256 thr (2m x 2n waves).
// 16B-unit XOR swizzle: physical slot p holds logical unit p^(row&3);
// staged via inverse-swizzled global src, read with the same XOR.
// EPI 0: bf16 store. EPI 1: +aux[col], softplus, bf16 store.
// EPI 2: +aux[row*N+col], fp32 store.
#define GBK 32
#define NKT 32

template<int EPI, int BN>
__global__ __launch_bounds__(256) void gemm_bf16(
    const ushort* __restrict__ A, const ushort* __restrict__ Bw,
    void* __restrict__ Co_, int N, const float* __restrict__ aux){
  __shared__ __align__(16) ushort lds[(128+BN)*GBK];   // 12KB or 16KB
  const int t  = threadIdx.x;
  const int bm = blockIdx.y * 128, bn = blockIdx.x * BN;

  // staging addressing (inverse-swizzled global source)
  const int r4 = t >> 2;
  const int k16 = (t & 3) ^ (r4 & 3);
  const ushort* gA = A  + (size_t)(bm + r4)*1024 + k16*8;
  const ushort* gB = Bw + (size_t)(bn + r4)*1024 + k16*8;
  const int wofs = (t >> 6) * 1024;   // per-wave byte offset inside a 4KB segment

  // fragment read addressing (same XOR)
  const int l  = t & 63, wv = t >> 6;
  const int wm = wv & 1, wn = wv >> 1;
  const int fr = l & 15, kb = l >> 4;
  const int sw = (kb ^ (fr & 3)) * 16;
  const int WN = BN/2;                       // wave col-tile (64 or 32)
  const int NF = BN/64;                      // B frags per wave / 2
  const int aofs = (wm*64 + fr)*64 + sw;     // A region, row stride 64B
  const int bofs = 8192 + (wn*WN + fr)*64 + sw;  // B region at byte 8192

  f32x4 acc[4][2*NF];
  #pragma unroll
  for (int m=0;m<4;m++){
    #pragma unroll
    for (int n=0;n<2*NF;n++) acc[m][n] = (f32x4){0.f,0.f,0.f,0.f};
  }

  char* Lb = (char*)lds;
  for (int kt = 0; kt < NKT; ++kt){
    const int ko = kt*GBK;
    gld16(gA + ko,           Lb +    0 + wofs);
    gld16(gA + ko + 64*1024, Lb + 4096 + wofs);
    gld16(gB + ko,           Lb + 8192 + wofs);
    if (BN == 128) gld16(gB + ko + 64*1024, Lb + 12288 + wofs);
    __syncthreads();
    short8 a[4], b[2*NF];
    #pragma unroll
    for (int m=0;m<4;m++) a[m] = *(const short8*)(Lb + aofs + m*1024);
    #pragma unroll
    for (int n=0;n<2*NF;n++) b[n] = *(const short8*)(Lb + bofs + n*1024);
    #pragma unroll
    for (int m=0;m<4;m++){
      #pragma unroll
      for (int n=0;n<2*NF;n++)
        acc[m][n] = __builtin_amdgcn_mfma_f32_16x16x32_bf16(a[m], b[n], acc[m][n], 0,0,0);
    }
    __syncthreads();
  }

  // C/D layout: col = lane&15, row = (lane>>4)*4 + reg   [m89-verified]
  #pragma unroll
  for (int m=0;m<4;m++){
    int row0 = bm + wm*64 + m*16 + kb*4;
    #pragma unroll
    for (int n=0;n<2*NF;n++){
      int col = bn + wn*WN + n*16 + fr;
      #pragma unroll
      for (int j=0;j<4;j++){
        int r = row0 + j;
        float v = acc[m][n][j];
        if (EPI==0){
          ((ushort*)Co_)[(size_t)r*N + col] = f2bf(v);
        } else if (EPI==1){
          v += aux[col];
          v = (v > 20.f) ? v : log1pf(__expf(v));
          ((ushort*)Co_)[(size_t)r*N + col] = f2bf(v);
        } else {
          v += aux[(size_t)r*N + col];
          ((float*)Co_)[(size_t)r*N + col] = v;
        }
      }
    }
  }
}

// ---------------- depthwise conv(K=3,pad=1) + silu -> bf16 ----------------
__global__ __launch_bounds__(256) void conv_silu_kernel(const ushort* __restrict__ xz,
        const float* __restrict__ cw, ushort* __restrict__ xch){
  int idx = blockIdx.x*256 + threadIdx.x;
  int d4  = idx & 255;
  int row = idx >> 8;
  int t = row & (LL-1);
  const ushort* p = xz + (size_t)row*E2V + d4*4;
  ushort4 u1 = *reinterpret_cast<const ushort4*>(p);
  ushort4 u0 = (t>0)    ? *reinterpret_cast<const ushort4*>(p - E2V) : make_ushort4(0,0,0,0);
  ushort4 u2 = (t<LL-1) ? *reinterpret_cast<const ushort4*>(p + E2V) : make_ushort4(0,0,0,0);
  int d = d4*4;
  float w[12];
  #pragma unroll
  for (int i=0;i<12;i++) w[i] = cw[d*3 + i];
  float4 o;
  o.x = bf2f(u0.x)*w[0] + bf2f(u1.x)*w[1]  + bf2f(u2.x)*w[2];
  o.y = bf2f(u0.y)*w[3] + bf2f(u1.y)*w[4]  + bf2f(u2.y)*w[5];
  o.z = bf2f(u0.z)*w[6] + bf2f(u1.z)*w[7]  + bf2f(u2.z)*w[8];
  o.w = bf2f(u0.w)*w[9] + bf2f(u1.w)*w[10] + bf2f(u2.w)*w[11];
  o.x = o.x / (1.f + __expf(-o.x));
  o.y = o.y / (1.f + __expf(-o.y));
  o.z = o.z / (1.f + __expf(-o.z));
  o.w = o.w / (1.f + __expf(-o.w));
  ushort4 H;
  H.x=f2bf(o.x); H.y=f2bf(o.y); H.z=f2bf(o.z); H.w=f2bf(o.w);
  *reinterpret_cast<ushort4*>(xch + (size_t)row*DIMV + d4*4) = H;
}

// ---------------- BC = xc @ W_x^T  (N=32) ----------------
__global__ __launch_bounds__(256) void bc_kernel(const ushort* __restrict__ xch,
        const float* __restrict__ wxt, float* __restrict__ bc){
  __shared__ ushort sh[8192];
  int tid = threadIdx.x;
  int row0 = blockIdx.x * 8;
  const ushort4* srcH = (const ushort4*)(xch + (size_t)row0*DIMV);
  #pragma unroll
  for (int i=0;i<8;i++)
    ((ushort4*)sh)[tid + i*256] = srcH[tid + i*256];
  __syncthreads();
  int r = tid >> 5, e = tid & 31;
  float acc = 0.f;
  for (int k=0;k<1024;k++){
    acc = fmaf(bf2f(sh[r*1024+k]), wxt[k*32+e], acc);
  }
  bc[(size_t)(row0 + r)*32 + e] = acc;
}

// ======== scan, one thread per channel d; S=16 state in registers ========
__global__ __launch_bounds__(256) void scan_p1(const ushort* __restrict__ dt,
        const float* __restrict__ bc, const float* __restrict__ A_log,
        float* __restrict__ F, float* __restrict__ P){
  __shared__ float sB[CLEN*32];
  int bid = blockIdx.x;                 // b*(NCHUNK*4) + c*4 + dblk
  int dblk = bid & 3;
  int c  = (bid >> 2) & (NCHUNK-1);
  int b  = bid >> 8;
  int tid = threadIdx.x;
  int d = dblk*256 + tid;
  int row0 = b*LL + c*CLEN;
  ((float4*)sB)[tid] = *((const float4*)(bc + (size_t)row0*32) + tid);
  float a[16];
  {
    const float4* ap = (const float4*)(A_log + d*16);
    #pragma unroll
    for (int q=0;q<4;q++){
      float4 v = ap[q];
      a[q*4+0]=-__expf(v.x); a[q*4+1]=-__expf(v.y);
      a[q*4+2]=-__expf(v.z); a[q*4+3]=-__expf(v.w);
    }
  }
  __syncthreads();
  float st[16];
  #pragma unroll
  for (int s=0;s<16;s++) st[s]=0.f;
  float sdt = 0.f;
  const ushort* dtp = dt + (size_t)row0*DIMV + d;
  for (int t=0;t<CLEN;t++){
    float dtv = bf2f(dtp[(size_t)t*DIMV]);
    sdt += dtv;
    float4 B0 = *(const float4*)&sB[t*32+0];
    float4 B1 = *(const float4*)&sB[t*32+4];
    float4 B2 = *(const float4*)&sB[t*32+8];
    float4 B3 = *(const float4*)&sB[t*32+12];
    float Bv[16] = {B0.x,B0.y,B0.z,B0.w,B1.x,B1.y,B1.z,B1.w,
                    B2.x,B2.y,B2.z,B2.w,B3.x,B3.y,B3.z,B3.w};
    #pragma unroll
    for (int s=0;s<16;s++){
      float dA = __expf(dtv*a[s]);
      st[s] = fmaf(st[s], dA, dtv*Bv[s]);
    }
  }
  size_t o = ((size_t)((b*NCHUNK + c)*DIMV + d))*16;
  #pragma unroll
  for (int q=0;q<4;q++){
    *(float4*)(F + o + q*4) = make_float4(st[q*4],st[q*4+1],st[q*4+2],st[q*4+3]);
    *(float4*)(P + o + q*4) = make_float4(__expf(sdt*a[q*4]),  __expf(sdt*a[q*4+1]),
                                          __expf(sdt*a[q*4+2]),__expf(sdt*a[q*4+3]));
  }
}

__global__ __launch_bounds__(256) void scan_p2(const float* __restrict__ F,
        const float* __restrict__ P, float* __restrict__ E){
  int idx = blockIdx.x*256 + threadIdx.x;   // BB*DIMV*SSV = 32768
  int b  = idx >> 14;
  int ds = idx & 16383;
  float e = 0.f;
  for (int c=0;c<NCHUNK;c++){
    size_t o = ((size_t)(b*NCHUNK + c) << 14) + ds;
    E[o] = e;
    e = fmaf(P[o], e, F[o]);
  }
}

__global__ __launch_bounds__(256) void scan_p3(const ushort* __restrict__ dt,
        const float* __restrict__ bc, const float* __restrict__ A_log,
        const float* __restrict__ E, const ushort* __restrict__ xch,
        const ushort* __restrict__ xz, const float* __restrict__ Dp,
        ushort* __restrict__ yh){
  __shared__ float sBC[CLEN*32];
  int bid = blockIdx.x;
  int dblk = bid & 3;
  int c  = (bid >> 2) & (NCHUNK-1);
  int b  = bid >> 8;
  int tid = threadIdx.x;
  int d = dblk*256 + tid;
  int row0 = b*LL + c*CLEN;
  ((float4*)sBC)[tid] = *((const float4*)(bc + (size_t)row0*32) + tid);
  float a[16];
  {
    const float4* ap = (const float4*)(A_log + d*16);
    #pragma unroll
    for (int q=0;q<4;q++){
      float4 v = ap[q];
      a[q*4+0]=-__expf(v.x); a[q*4+1]=-__expf(v.y);
      a[q*4+2]=-__expf(v.z); a[q*4+3]=-__expf(v.w);
    }
  }
  float st[16];
  {
    size_t o = ((size_t)((b*NCHUNK + c)*DIMV + d))*16;
    #pragma unroll
    for (int q=0;q<4;q++){
      float4 v = *(const float4*)(E + o + q*4);
      st[q*4]=v.x; st[q*4+1]=v.y; st[q*4+2]=v.z; st[q*4+3]=v.w;
    }
  }
  float Dv = Dp[d];
  __syncthreads();
  const ushort* dtp = dt + (size_t)row0*DIMV + d;
  for (int t=0;t<CLEN;t++){
    float dtv = bf2f(dtp[(size_t)t*DIMV]);
    float4 B0 = *(const float4*)&sBC[t*32+0];
    float4 B1 = *(const float4*)&sBC[t*32+4];
    float4 B2 = *(const float4*)&sBC[t*32+8];
    float4 B3 = *(const float4*)&sBC[t*32+12];
    float4 C0 = *(const float4*)&sBC[t*32+16];
    float4 C1 = *(const float4*)&sBC[t*32+20];
    float4 C2 = *(const float4*)&sBC[t*32+24];
    float4 C3 = *(const float4*)&sBC[t*32+28];
    float Bv[16] = {B0.x,B0.y,B0.z,B0.w,B1.x,B1.y,B1.z,B1.w,
                    B2.x,B2.y,B2.z,B2.w,B3.x,B3.y,B3.z,B3.w};
    float Cv[16] = {C0.x,C0.y,C0.z,C0.w,C1.x,C1.y,C1.z,C1.w,
                    C2.x,C2.y,C2.z,C2.w,C3.x,C3.y,C3.z,C3.w};
    float y = 0.f;
    #pragma unroll
    for (int s=0;s<16;s++){
      float dA = __expf(dtv*a[s]);
      st[s] = fmaf(st[s], dA, dtv*Bv[s]);
      y = fmaf(st[s], Cv[s], y);
    }
    int row = row0 + t;
    size_t ofs = (size_t)row*DIMV + d;
    float xcv = bf2f(xch[ofs]);
    float zv  = bf2f(xz[(size_t)row*E2V + INNERV + d]);
    float sz  = zv / (1.f + __expf(-zv));
    yh[ofs] = f2bf((y + Dv*xcv)*sz);
  }
}

extern "C" void kernel_launch(void* const* d_in, const int* in_sizes, int n_in,
                              void* d_out, int out_size, void* d_ws, size_t ws_size,
                              hipStream_t stream){
  const float* x     = (const float*)d_in[0];
  const float* gamma = (const float*)d_in[1];
  const float* beta  = (const float*)d_in[2];
  const float* W_in  = (const float*)d_in[3];
  const float* cw    = (const float*)d_in[4];
  const float* W_x   = (const float*)d_in[5];
  const float* W_dt  = (const float*)d_in[6];
  const float* b_dt  = (const float*)d_in[7];
  const float* A_log = (const float*)d_in[8];
  const float* Dp    = (const float*)d_in[9];
  const float* W_out = (const float*)d_in[10];
  float* out = (float*)d_out;
  float* ws  = (float*)d_ws;
  const size_t MB = (size_t)1 << 20;   // 1M floats
  // layout (float units); bf16 buffer of N elems occupies N/2 float slots.
  ushort* xzh = (ushort*)ws;                      // 8M bf16 -> [0,4M)
  ushort* hh  = (ushort*)(ws + 4*MB);             // 4M bf16 -> [4M,6M); dead after gemm0
  ushort* yh  = (ushort*)(ws + 4*MB);             // p3 writes (hh dead)
  ushort* xch = (ushort*)(ws + 6*MB);             // [6M,8M)
  ushort* dtb = (ushort*)(ws + 8*MB);             // 4M bf16 -> [8M,10M)
  float*  F   = ws + 10*MB;                       // [10M,12M)
  float*  P   = ws + 12*MB;                       // [12M,14M)
  float*  E   = ws + 14*MB;                       // [14M,16M)
  ushort* Wih = (ushort*)(ws + 16*MB);            // [16M,17M)
  ushort* Wdh = (ushort*)(ws + 17*MB);            // [17M,17.5M)
  ushort* Woh = (ushort*)(ws + 17*MB + 512*1024); // [17.5M,18M)
  float*  bcb = ws + 18*MB;                       // 128K floats
  float*  wxt = ws + 18*MB + 128*1024;            // 32K floats

  init_kernel<<<4224, 256, 0, stream>>>(W_in, W_dt, W_out, W_x, Wih, Wdh, Woh, wxt);
  ln_kernel<<<MMV, 256, 0, stream>>>(x, gamma, beta, hh);
  gemm_bf16<0,128><<<dim3(E2V/128, MMV/128), 256, 0, stream>>>(hh, Wih, xzh, E2V, nullptr);
  conv_silu_kernel<<<(MMV*(DIMV/4))/256, 256, 0, stream>>>(xzh, cw, xch);
  gemm_bf16<1,64><<<dim3(INNERV/64, MMV/128), 256, 0, stream>>>(xch, Wdh, dtb, INNERV, b_dt);
  bc_kernel<<<MMV/8, 256, 0, stream>>>(xch, wxt, bcb);
  scan_p1<<<BB*NCHUNK*(DIMV/256), 256, 0, stream>>>(dtb, bcb, A_log, F, P);
  scan_p2<<<(BB*DIMV*SSV)/256, 256, 0, stream>>>(F, P, E);
  scan_p3<<<BB*NCHUNK*(DIMV/256), 256, 0, stream>>>(dtb, bcb, A_log, E, xch, xzh, Dp, yh);
  gemm_bf16<2,64><<<dim3(DIMV/64, MMV/128), 256, 0, stream>>>(yh, Woh, out, DIMV, x);
}

// Round 10
// 160.771 us; speedup vs baseline: 3.9453x; 1.2136x over previous
//
#include <hip/hip_runtime.h>
#include <math.h>

#define BB 2
#define LL 2048
#define DIMV 1024
#define SSV 16
#define INNERV 1024
#define E2V 2048
#define MMV (BB*LL)      // 4096 rows
#define NCHUNK 64
#define CLEN 32          // LL / NCHUNK

typedef __attribute__((ext_vector_type(8))) short short8;   // 8 bf16 = 4 VGPRs (MFMA A/B frag)
typedef __attribute__((ext_vector_type(4))) float f32x4;    // MFMA C/D frag

static __device__ __forceinline__ float4 ld4(const float* p){
  return *reinterpret_cast<const float4*>(p);
}
// RNE fp32 -> bf16 (bit-level)
static __device__ __forceinline__ ushort f2bf(float x){
  unsigned u = __float_as_uint(x);
  unsigned r = (u + 0x7fffu + ((u >> 16) & 1u)) >> 16;
  return (ushort)r;
}
static __device__ __forceinline__ float bf2f(ushort h){
  return __uint_as_float(((unsigned)h) << 16);
}
// async global->LDS, 16B per lane; lds dest wave-uniform base + lane*16
static __device__ __forceinline__ void gld16(const void* g, void* l){
  __builtin_amdgcn_global_load_lds(
      (const __attribute__((address_space(1))) void*)g,
      (__attribute__((address_space(3))) void*)l, 16, 0, 0);
}

// ---------- fused init (weight casts + W_x transpose) + LayerNorm ----------
// blocks [0,4224): init.  [4224, 4224+MMV): LN row = blockIdx.x-4224.
__global__ __launch_bounds__(256) void ln_init(
        const float* __restrict__ x, const float* __restrict__ gamma,
        const float* __restrict__ beta, ushort* __restrict__ hh,
        const float* __restrict__ W_in, const float* __restrict__ W_dt,
        const float* __restrict__ W_out, const float* __restrict__ wx,
        ushort* __restrict__ Wih, ushort* __restrict__ Wdh,
        ushort* __restrict__ Woh, float* __restrict__ wxt){
  __shared__ float red[8];
  if (blockIdx.x < 4224){
    int idx = blockIdx.x*256 + threadIdx.x;
    if (idx < 1024*1024){
      const float* src; ushort* dst; int i;
      if (idx < 512*1024){ src = W_in;  dst = Wih; i = idx; }
      else if (idx < 768*1024){ src = W_dt;  dst = Wdh; i = idx - 512*1024; }
      else { src = W_out; dst = Woh; i = idx - 768*1024; }
      float4 v = ld4(src + (size_t)i*4);
      ushort4 H;
      H.x=f2bf(v.x); H.y=f2bf(v.y); H.z=f2bf(v.z); H.w=f2bf(v.w);
      *reinterpret_cast<ushort4*>(dst + (size_t)i*4) = H;
    } else {
      int j = idx - 1024*1024;           // [0, 32768)
      int e = j >> 10, k = j & 1023;
      wxt[k*32 + e] = wx[j];
    }
    return;
  }
  int row = blockIdx.x - 4224;
  int tid = threadIdx.x;
  const float* xr = x + (size_t)row*DIMV;
  float4 v = ld4(xr + tid*4);
  float s  = v.x+v.y+v.z+v.w;
  float s2 = v.x*v.x+v.y*v.y+v.z*v.z+v.w*v.w;
  for (int o=32;o;o>>=1){ s += __shfl_down(s,o); s2 += __shfl_down(s2,o); }
  int wid = tid>>6, lane = tid&63;
  if (lane==0){ red[wid]=s; red[4+wid]=s2; }
  __syncthreads();
  s  = red[0]+red[1]+red[2]+red[3];
  s2 = red[4]+red[5]+red[6]+red[7];
  float mu  = s*(1.f/DIMV);
  float var = s2*(1.f/DIMV) - mu*mu;
  float rstd = rsqrtf(var + 1e-5f);
  float4 g = ld4(gamma + tid*4), be = ld4(beta + tid*4);
  ushort4 H;
  H.x = f2bf((v.x-mu)*rstd*g.x + be.x);
  H.y = f2bf((v.y-mu)*rstd*g.y + be.y);
  H.z = f2bf((v.z-mu)*rstd*g.z + be.z);
  H.w = f2bf((v.w-mu)*rstd*g.w + be.w);
  *reinterpret_cast<ushort4*>(hh + (size_t)row*DIMV + tid*4) = H;
}

// ============ bf16 MFMA GEMM body: Co[M,N] = A[M,1024]*Bw[N,1024]^T ============
// m97-canonical 2-barrier-per-K-step, SINGLE LDS buffer. BK=64 (NKT=16).
// LDS rows are 128B (64 bf16); 8x16B units/row, XOR swizzle unit^=(row&7),
// staged via inverse-swizzled global source, read with the same XOR.
// EPI 0: bf16 store. EPI 1: +aux[col], softplus, bf16 store.
// EPI 2: +aux[row*N+col], fp32 store.
#define GBK 64
#define NKT 16

template<int EPI, int BN>
static __device__ __forceinline__ void gemm_body(ushort* lds,
    const ushort* __restrict__ A, const ushort* __restrict__ Bw,
    void* __restrict__ Co_, int N, const float* __restrict__ aux,
    int bm, int bn){
  const int t  = threadIdx.x;

  // staging: thread t -> physical unit (t&7) of row (t>>3) within a 32-row
  // chunk; fetches logical unit (t&7)^(row&7).
  const int rr  = t >> 3;                 // 0..31
  const int k16 = (t & 7) ^ (rr & 7);
  const ushort* gA = A  + (size_t)(bm + rr)*1024 + k16*8;
  const ushort* gB = Bw + (size_t)(bn + rr)*1024 + k16*8;
  const int wofs = (t >> 6) * 1024;       // wave offset inside a 4KB chunk

  // fragment read addressing
  const int l  = t & 63, wv = t >> 6;
  const int wm = wv & 1, wn = wv >> 1;
  const int fr = l & 15, kb = l >> 4;
  const int WN = BN/2;                    // wave col-tile (64 or 32)
  const int NF = BN/64;

  f32x4 acc[4][2*NF];
  #pragma unroll
  for (int m=0;m<4;m++){
    #pragma unroll
    for (int n=0;n<2*NF;n++) acc[m][n] = (f32x4){0.f,0.f,0.f,0.f};
  }

  char* Lb = (char*)lds;
  for (int kt = 0; kt < NKT; ++kt){
    const int ko = kt*GBK;
    gld16(gA + ko,           Lb +     0 + wofs);
    gld16(gA + ko + 32*1024, Lb +  4096 + wofs);
    gld16(gA + ko + 64*1024, Lb +  8192 + wofs);
    gld16(gA + ko + 96*1024, Lb + 12288 + wofs);
    gld16(gB + ko,           Lb + 16384 + wofs);
    gld16(gB + ko + 32*1024, Lb + 20480 + wofs);
    if (BN == 128){
      gld16(gB + ko + 64*1024, Lb + 24576 + wofs);
      gld16(gB + ko + 96*1024, Lb + 28672 + wofs);
    }
    __syncthreads();
    short8 a[4][2], b[2*NF][2];
    #pragma unroll
    for (int m=0;m<4;m++){
      int row = wm*64 + m*16 + fr;
      #pragma unroll
      for (int ks=0;ks<2;ks++)
        a[m][ks] = *(const short8*)(Lb + row*128 + (((ks*4+kb)^(fr&7))*16));
    }
    #pragma unroll
    for (int n=0;n<2*NF;n++){
      int row = wn*WN + n*16 + fr;
      #pragma unroll
      for (int ks=0;ks<2;ks++)
        b[n][ks] = *(const short8*)(Lb + 16384 + row*128 + (((ks*4+kb)^(fr&7))*16));
    }
    #pragma unroll
    for (int ks=0;ks<2;ks++){
      #pragma unroll
      for (int m=0;m<4;m++){
        #pragma unroll
        for (int n=0;n<2*NF;n++)
          acc[m][n] = __builtin_amdgcn_mfma_f32_16x16x32_bf16(a[m][ks], b[n][ks], acc[m][n], 0,0,0);
      }
    }
    __syncthreads();
  }

  // C/D layout: col = lane&15, row = (lane>>4)*4 + reg   [m89-verified]
  #pragma unroll
  for (int m=0;m<4;m++){
    int row0 = bm + wm*64 + m*16 + kb*4;
    #pragma unroll
    for (int n=0;n<2*NF;n++){
      int col = bn + wn*WN + n*16 + fr;
      #pragma unroll
      for (int j=0;j<4;j++){
        int r = row0 + j;
        float v = acc[m][n][j];
        if (EPI==0){
          ((ushort*)Co_)[(size_t)r*N + col] = f2bf(v);
        } else if (EPI==1){
          v += aux[col];
          v = (v > 20.f) ? v : log1pf(__expf(v));
          ((ushort*)Co_)[(size_t)r*N + col] = f2bf(v);
        } else {
          v += aux[(size_t)r*N + col];
          ((float*)Co_)[(size_t)r*N + col] = v;
        }
      }
    }
  }
}

template<int EPI, int BN>
__global__ __launch_bounds__(256) void gemm_bf16(
    const ushort* __restrict__ A, const ushort* __restrict__ Bw,
    void* __restrict__ Co_, int N, const float* __restrict__ aux){
  __shared__ __align__(16) ushort lds[(128+BN)*GBK];
  gemm_body<EPI,BN>(lds, A, Bw, Co_, N, aux, blockIdx.y*128, blockIdx.x*BN);
}

// ---------------- BC body: bc[row,0:32] = xc_row . W_x^T ----------------
static __device__ __forceinline__ void bc_body(ushort* sh,
    const ushort* __restrict__ xch, const float* __restrict__ wxt,
    float* __restrict__ bc, int blk){
  int tid = threadIdx.x;
  int row0 = blk * 8;
  const ushort4* srcH = (const ushort4*)(xch + (size_t)row0*DIMV);
  #pragma unroll
  for (int i=0;i<8;i++)
    ((ushort4*)sh)[tid + i*256] = srcH[tid + i*256];
  __syncthreads();
  int r = tid >> 5, e = tid & 31;
  float acc = 0.f;
  for (int k=0;k<1024;k++){
    acc = fmaf(bf2f(sh[r*1024+k]), wxt[k*32+e], acc);
  }
  bc[(size_t)(row0 + r)*32 + e] = acc;
}

// ------- fused: gemm1 (dt = softplus(xc@W_dt^T + b)) + bc -------
// blockIdx.y in [0,32): gemm tile. [32,64): bc block (y-32)*16 + x.
__global__ __launch_bounds__(256) void gemm1_bc(
    const ushort* __restrict__ xch, const ushort* __restrict__ Wdh,
    ushort* __restrict__ dtb, const float* __restrict__ b_dt,
    const float* __restrict__ wxt, float* __restrict__ bcb){
  __shared__ __align__(16) ushort lds[(128+64)*GBK];   // 24KB (>=16KB for bc)
  if (blockIdx.y < 32){
    gemm_body<1,64>(lds, xch, Wdh, dtb, INNERV, b_dt, blockIdx.y*128, blockIdx.x*64);
  } else {
    bc_body(lds, xch, wxt, bcb, (blockIdx.y-32)*16 + blockIdx.x);
  }
}

// ---------------- depthwise conv(K=3,pad=1) + silu -> bf16 ----------------
__global__ __launch_bounds__(256) void conv_silu_kernel(const ushort* __restrict__ xz,
        const float* __restrict__ cw, ushort* __restrict__ xch){
  int idx = blockIdx.x*256 + threadIdx.x;
  int d4  = idx & 255;
  int row = idx >> 8;
  int t = row & (LL-1);
  const ushort* p = xz + (size_t)row*E2V + d4*4;
  ushort4 u1 = *reinterpret_cast<const ushort4*>(p);
  ushort4 u0 = (t>0)    ? *reinterpret_cast<const ushort4*>(p - E2V) : make_ushort4(0,0,0,0);
  ushort4 u2 = (t<LL-1) ? *reinterpret_cast<const ushort4*>(p + E2V) : make_ushort4(0,0,0,0);
  int d = d4*4;
  float w[12];
  #pragma unroll
  for (int i=0;i<12;i++) w[i] = cw[d*3 + i];
  float4 o;
  o.x = bf2f(u0.x)*w[0] + bf2f(u1.x)*w[1]  + bf2f(u2.x)*w[2];
  o.y = bf2f(u0.y)*w[3] + bf2f(u1.y)*w[4]  + bf2f(u2.y)*w[5];
  o.z = bf2f(u0.z)*w[6] + bf2f(u1.z)*w[7]  + bf2f(u2.z)*w[8];
  o.w = bf2f(u0.w)*w[9] + bf2f(u1.w)*w[10] + bf2f(u2.w)*w[11];
  o.x = o.x / (1.f + __expf(-o.x));
  o.y = o.y / (1.f + __expf(-o.y));
  o.z = o.z / (1.f + __expf(-o.z));
  o.w = o.w / (1.f + __expf(-o.w));
  ushort4 H;
  H.x=f2bf(o.x); H.y=f2bf(o.y); H.z=f2bf(o.z); H.w=f2bf(o.w);
  *reinterpret_cast<ushort4*>(xch + (size_t)row*DIMV + d4*4) = H;
}

// ======== scan, one thread per channel d; S=16 state in registers ========
__global__ __launch_bounds__(256) void scan_p1(const ushort* __restrict__ dt,
        const float* __restrict__ bc, const float* __restrict__ A_log,
        float* __restrict__ F, float* __restrict__ P){
  __shared__ float sB[CLEN*32];
  int bid = blockIdx.x;                 // b*(NCHUNK*4) + c*4 + dblk
  int dblk = bid & 3;
  int c  = (bid >> 2) & (NCHUNK-1);
  int b  = bid >> 8;
  int tid = threadIdx.x;
  int d = dblk*256 + tid;
  int row0 = b*LL + c*CLEN;
  ((float4*)sB)[tid] = *((const float4*)(bc + (size_t)row0*32) + tid);
  float a[16];
  {
    const float4* ap = (const float4*)(A_log + d*16);
    #pragma unroll
    for (int q=0;q<4;q++){
      float4 v = ap[q];
      a[q*4+0]=-__expf(v.x); a[q*4+1]=-__expf(v.y);
      a[q*4+2]=-__expf(v.z); a[q*4+3]=-__expf(v.w);
    }
  }
  __syncthreads();
  float st[16];
  #pragma unroll
  for (int s=0;s<16;s++) st[s]=0.f;
  float sdt = 0.f;
  const ushort* dtp = dt + (size_t)row0*DIMV + d;
  for (int t=0;t<CLEN;t++){
    float dtv = bf2f(dtp[(size_t)t*DIMV]);
    sdt += dtv;
    float4 B0 = *(const float4*)&sB[t*32+0];
    float4 B1 = *(const float4*)&sB[t*32+4];
    float4 B2 = *(const float4*)&sB[t*32+8];
    float4 B3 = *(const float4*)&sB[t*32+12];
    float Bv[16] = {B0.x,B0.y,B0.z,B0.w,B1.x,B1.y,B1.z,B1.w,
                    B2.x,B2.y,B2.z,B2.w,B3.x,B3.y,B3.z,B3.w};
    #pragma unroll
    for (int s=0;s<16;s++){
      float dA = __expf(dtv*a[s]);
      st[s] = fmaf(st[s], dA, dtv*Bv[s]);
    }
  }
  size_t o = ((size_t)((b*NCHUNK + c)*DIMV + d))*16;
  #pragma unroll
  for (int q=0;q<4;q++){
    *(float4*)(F + o + q*4) = make_float4(st[q*4],st[q*4+1],st[q*4+2],st[q*4+3]);
    *(float4*)(P + o + q*4) = make_float4(__expf(sdt*a[q*4]),  __expf(sdt*a[q*4+1]),
                                          __expf(sdt*a[q*4+2]),__expf(sdt*a[q*4+3]));
  }
}

__global__ __launch_bounds__(256) void scan_p2(const float* __restrict__ F,
        const float* __restrict__ P, float* __restrict__ E){
  int idx = blockIdx.x*256 + threadIdx.x;   // BB*DIMV*SSV = 32768
  int b  = idx >> 14;
  int ds = idx & 16383;
  float e = 0.f;
  for (int c=0;c<NCHUNK;c++){
    size_t o = ((size_t)(b*NCHUNK + c) << 14) + ds;
    E[o] = e;
    e = fmaf(P[o], e, F[o]);
  }
}

__global__ __launch_bounds__(256) void scan_p3(const ushort* __restrict__ dt,
        const float* __restrict__ bc, const float* __restrict__ A_log,
        const float* __restrict__ E, const ushort* __restrict__ xch,
        const ushort* __restrict__ xz, const float* __restrict__ Dp,
        ushort* __restrict__ yh){
  __shared__ float sBC[CLEN*32];
  int bid = blockIdx.x;
  int dblk = bid & 3;
  int c  = (bid >> 2) & (NCHUNK-1);
  int b  = bid >> 8;
  int tid = threadIdx.x;
  int d = dblk*256 + tid;
  int row0 = b*LL + c*CLEN;
  ((float4*)sBC)[tid] = *((const float4*)(bc + (size_t)row0*32) + tid);
  float a[16];
  {
    const float4* ap = (const float4*)(A_log + d*16);
    #pragma unroll
    for (int q=0;q<4;q++){
      float4 v = ap[q];
      a[q*4+0]=-__expf(v.x); a[q*4+1]=-__expf(v.y);
      a[q*4+2]=-__expf(v.z); a[q*4+3]=-__expf(v.w);
    }
  }
  float st[16];
  {
    size_t o = ((size_t)((b*NCHUNK + c)*DIMV + d))*16;
    #pragma unroll
    for (int q=0;q<4;q++){
      float4 v = *(const float4*)(E + o + q*4);
      st[q*4]=v.x; st[q*4+1]=v.y; st[q*4+2]=v.z; st[q*4+3]=v.w;
    }
  }
  float Dv = Dp[d];
  __syncthreads();
  const ushort* dtp = dt + (size_t)row0*DIMV + d;
  for (int t=0;t<CLEN;t++){
    float dtv = bf2f(dtp[(size_t)t*DIMV]);
    float4 B0 = *(const float4*)&sBC[t*32+0];
    float4 B1 = *(const float4*)&sBC[t*32+4];
    float4 B2 = *(const float4*)&sBC[t*32+8];
    float4 B3 = *(const float4*)&sBC[t*32+12];
    float4 C0 = *(const float4*)&sBC[t*32+16];
    float4 C1 = *(const float4*)&sBC[t*32+20];
    float4 C2 = *(const float4*)&sBC[t*32+24];
    float4 C3 = *(const float4*)&sBC[t*32+28];
    float Bv[16] = {B0.x,B0.y,B0.z,B0.w,B1.x,B1.y,B1.z,B1.w,
                    B2.x,B2.y,B2.z,B2.w,B3.x,B3.y,B3.z,B3.w};
    float Cv[16] = {C0.x,C0.y,C0.z,C0.w,C1.x,C1.y,C1.z,C1.w,
                    C2.x,C2.y,C2.z,C2.w,C3.x,C3.y,C3.z,C3.w};
    float y = 0.f;
    #pragma unroll
    for (int s=0;s<16;s++){
      float dA = __expf(dtv*a[s]);
      st[s] = fmaf(st[s], dA, dtv*Bv[s]);
      y = fmaf(st[s], Cv[s], y);
    }
    int row = row0 + t;
    size_t ofs = (size_t)row*DIMV + d;
    float xcv = bf2f(xch[ofs]);
    float zv  = bf2f(xz[(size_t)row*E2V + INNERV + d]);
    float sz  = zv / (1.f + __expf(-zv));
    yh[ofs] = f2bf((y + Dv*xcv)*sz);
  }
}

extern "C" void kernel_launch(void* const* d_in, const int* in_sizes, int n_in,
                              void* d_out, int out_size, void* d_ws, size_t ws_size,
                              hipStream_t stream){
  const float* x     = (const float*)d_in[0];
  const float* gamma = (const float*)d_in[1];
  const float* beta  = (const float*)d_in[2];
  const float* W_in  = (const float*)d_in[3];
  const float* cw    = (const float*)d_in[4];
  const float* W_x   = (const float*)d_in[5];
  const float* W_dt  = (const float*)d_in[6];
  const float* b_dt  = (const float*)d_in[7];
  const float* A_log = (const float*)d_in[8];
  const float* Dp    = (const float*)d_in[9];
  const float* W_out = (const float*)d_in[10];
  float* out = (float*)d_out;
  float* ws  = (float*)d_ws;
  const size_t MB = (size_t)1 << 20;   // 1M floats
  // layout (float units); bf16 buffer of N elems occupies N/2 float slots.
  ushort* xzh = (ushort*)ws;                      // 8M bf16 -> [0,4M)
  ushort* hh  = (ushort*)(ws + 4*MB);             // 4M bf16 -> [4M,6M); dead after gemm0
  ushort* yh  = (ushort*)(ws + 4*MB);             // p3 writes (hh dead)
  ushort* xch = (ushort*)(ws + 6*MB);             // [6M,8M)
  ushort* dtb = (ushort*)(ws + 8*MB);             // 4M bf16 -> [8M,10M)
  float*  F   = ws + 10*MB;                       // [10M,12M)
  float*  P   = ws + 12*MB;                       // [12M,14M)
  float*  E   = ws + 14*MB;                       // [14M,16M)
  ushort* Wih = (ushort*)(ws + 16*MB);            // [16M,17M)
  ushort* Wdh = (ushort*)(ws + 17*MB);            // [17M,17.5M)
  ushort* Woh = (ushort*)(ws + 17*MB + 512*1024); // [17.5M,18M)
  float*  bcb = ws + 18*MB;                       // 128K floats
  float*  wxt = ws + 18*MB + 128*1024;            // 32K floats

  ln_init<<<4224 + MMV, 256, 0, stream>>>(x, gamma, beta, hh,
                                          W_in, W_dt, W_out, W_x,
                                          Wih, Wdh, Woh, wxt);
  gemm_bf16<0,128><<<dim3(E2V/128, MMV/128), 256, 0, stream>>>(hh, Wih, xzh, E2V, nullptr);
  conv_silu_kernel<<<(MMV*(DIMV/4))/256, 256, 0, stream>>>(xzh, cw, xch);
  gemm1_bc<<<dim3(16, 64), 256, 0, stream>>>(xch, Wdh, dtb, b_dt, wxt, bcb);
  scan_p1<<<BB*NCHUNK*(DIMV/256), 256, 0, stream>>>(dtb, bcb, A_log, F, P);
  scan_p2<<<(BB*DIMV*SSV)/256, 256, 0, stream>>>(F, P, E);
  scan_p3<<<BB*NCHUNK*(DIMV/256), 256, 0, stream>>>(dtb, bcb, A_log, E, xch, xzh, Dp, yh);
  gemm_bf16<2,64><<<dim3(DIMV/64, MMV/128), 256, 0, stream>>>(yh, Woh, out, DIMV, x);
}